// Round 5
// baseline (491.437 us; speedup 1.0000x reference)
//
#include <hip/hip_runtime.h>
#include <cmath>

#define T_SEQ 2048
#define NH    16
#define HD    64
#define DM    1024
#define BATCH 4

typedef __attribute__((ext_vector_type(8))) short s16x8;
typedef __attribute__((ext_vector_type(8))) _Float16 f16x8;
typedef __attribute__((ext_vector_type(4))) float f32x4;
typedef unsigned short ushort_t;

__device__ __forceinline__ ushort_t f2h(float x) {   // rne fp32->fp16
    union { _Float16 h; ushort_t u; } v; v.h = (_Float16)x; return v.u;
}
__device__ __forceinline__ float h2f(ushort_t u) {
    union { ushort_t u; _Float16 h; } v; v.u = u; return (float)v.h;
}
// raw v_exp_f32 (2^x) — __exp2f doesn't exist on this ROCm (R10 compile fail)
__device__ __forceinline__ float exp2_raw(float x) {
    return __builtin_amdgcn_exp2f(x);
}

// async global->LDS DMA, 16 B per lane (verified R7/R9).
__device__ __forceinline__ void dma16(const void* g, const void* l) {
    __builtin_amdgcn_global_load_lds(
        (const __attribute__((address_space(1))) unsigned int*)(unsigned long long)g,
        (__attribute__((address_space(3))) unsigned int*)(unsigned int)(unsigned long long)l,
        16, 0, 0);
}

// -------------------------------------------------------------------------
// Kernel 1: mask prep. Emits ADDITIVE bias: 0.0 (attend) / -1e30 (pad).
// -------------------------------------------------------------------------
__global__ void maskprep_kernel(const int* __restrict__ pad, float* __restrict__ valid)
{
    __shared__ int sall[256];
    const int b = blockIdx.x;
    const int t = threadIdx.x;
    int allp = 1;
    for (int i = t; i < T_SEQ; i += 256) allp &= (pad[b*T_SEQ + i] != 0) ? 1 : 0;
    sall[t] = allp;
    __syncthreads();
    for (int s = 128; s > 0; s >>= 1) {
        if (t < s) sall[t] &= sall[t + s];
        __syncthreads();
    }
    const int ap = sall[0];
    for (int i = t; i < T_SEQ; i += 256) {
        const int p = (pad[b*T_SEQ + i] != 0) ? 1 : 0;
        valid[b*T_SEQ + i] = (p && !ap) ? -1e30f : 0.0f;
    }
}

// -------------------------------------------------------------------------
// Kernel 2: weight transpose+split. W[K][N] -> Th/Tl[N][K] as fp16 hi/lo
// of (32*w) — scaling keeps the lo part out of fp16 subnormal range.
// GEMM epilogue multiplies acc by 1/32.
// -------------------------------------------------------------------------
__global__ __launch_bounds__(256)
void transpose_split_kernel(const float* __restrict__ W,
                            ushort_t* __restrict__ Th, ushort_t* __restrict__ Tl,
                            int K, int N)
{
    __shared__ float T[64][68];
    const int tid = threadIdx.x;
    const int n0 = blockIdx.x * 64;
    const int k0 = blockIdx.y * 64;
#pragma unroll
    for (int i = 0; i < 4; ++i) {
        const int kr = (tid >> 4) + i*16;
        const int nc = (tid & 15) * 4;
        const float4 v = *(const float4*)&W[(size_t)(k0 + kr)*N + n0 + nc];
        T[nc+0][kr] = v.x; T[nc+1][kr] = v.y; T[nc+2][kr] = v.z; T[nc+3][kr] = v.w;
    }
    __syncthreads();
#pragma unroll
    for (int i = 0; i < 4; ++i) {
        const int nr = (tid >> 4) + i*16;
        const int kc = (tid & 15) * 4;
        ushort_t h[4], l[4];
#pragma unroll
        for (int j = 0; j < 4; ++j) {
            const float x = T[nr][kc + j] * 32.0f;
            h[j] = f2h(x);
            l[j] = f2h(x - h2f(h[j]));
        }
        const size_t off = (size_t)(n0 + nr)*K + k0 + kc;
        *(short4*)&Th[off] = make_short4((short)h[0], (short)h[1], (short)h[2], (short)h[3]);
        *(short4*)&Tl[off] = make_short4((short)l[0], (short)l[1], (short)l[2], (short)l[3]);
    }
}

// -------------------------------------------------------------------------
// Kernel 2b: row-major fp32 -> single fp16 (tokens).
// -------------------------------------------------------------------------
__global__ __launch_bounds__(256)
void split_kernel(const float* __restrict__ X, ushort_t* __restrict__ H)
{
    const int i = blockIdx.x * 256 + threadIdx.x;     // float4 index
    const float4 v = ((const float4*)X)[i];
    *(short4*)&H[(size_t)i*4] = make_short4(
        (short)f2h(v.x), (short)f2h(v.y), (short)f2h(v.z), (short)f2h(v.w));
}

// -------------------------------------------------------------------------
// Kernel 3/5: fp16 2-product MFMA GEMM. A = single fp16 activations,
// B = split fp16 hi/lo of 32*W. acc*(1/32)+bias in epilogue.
// 64x128xBK32 block tile, 32x64 wave tile, 16 MFMA per wave-K-step.
// -------------------------------------------------------------------------
template<int EPI>
__global__ __launch_bounds__(256)
void mfma_gemm_kernel(const ushort_t* __restrict__ Atf,
                      const ushort_t* __restrict__ BTh, const ushort_t* __restrict__ BTl,
                      const float* __restrict__ bias,
                      float* __restrict__ O0,
                      ushort_t* __restrict__ Qf,
                      ushort_t* __restrict__ Khf, ushort_t* __restrict__ Klf,
                      ushort_t* __restrict__ Vthf, ushort_t* __restrict__ Vtlf,
                      int M, int N, int K)
{
    __shared__ __align__(16) char smem[34816];
    char* smA  = smem;             // [64][32] fp16 = 4 KB
    char* smBh = smem + 4096;      // [128][32] fp16 = 8 KB
    char* smBl = smem + 12288;

    const int tid  = threadIdx.x;
    const int w    = tid >> 6;
    const int ln   = tid & 63;
    const int lx   = ln & 15;
    const int quad = ln >> 4;
    const int mw   = (w >> 1) * 32;
    const int nw   = (w & 1) * 64;
    const int m0   = blockIdx.y * 64;
    const int n0   = blockIdx.x * 128;

    const size_t gaA = (size_t)(m0 + w*16 + (ln >> 2))*K + (ln & 3)*8;
    const size_t gaB = (size_t)(n0 + w*32 + (ln >> 2))*K + (ln & 3)*8;
    const int ldsA = (w*64 + ln)*16;
    const int ldsB = (w*128 + ln)*16;

#define ISSUE_DMA(kk) do {                                               \
        dma16(Atf + gaA + (kk),        smA  + ldsA);                     \
        dma16(BTh + gaB + (kk),        smBh + ldsB);                     \
        dma16(BTh + gaB + 16*K + (kk), smBh + ldsB + 1024);              \
        dma16(BTl + gaB + (kk),        smBl + ldsB);                     \
        dma16(BTl + gaB + 16*K + (kk), smBl + ldsB + 1024);              \
    } while (0)

    f32x4 acc[2][4];
#pragma unroll
    for (int mt = 0; mt < 2; ++mt)
#pragma unroll
        for (int nt = 0; nt < 4; ++nt) acc[mt][nt] = (f32x4){0.f,0.f,0.f,0.f};

    ISSUE_DMA(0);

    for (int kk = 0; kk < K; kk += 32) {
        __syncthreads();

        f16x8 bfh[4], bfl[4];
#pragma unroll
        for (int nt = 0; nt < 4; ++nt) {
            const int off = (nw + nt*16 + lx)*64 + quad*16;
            bfh[nt] = *(const f16x8*)(smBh + off);
            bfl[nt] = *(const f16x8*)(smBl + off);
        }
        f16x8 af0, af1;
        {
            af0 = *(const f16x8*)(smA + (mw + lx)*64 + quad*16);
            af1 = *(const f16x8*)(smA + (mw + 16 + lx)*64 + quad*16);
        }
        __syncthreads();
        if (kk + 32 < K) ISSUE_DMA(kk + 32);

        __builtin_amdgcn_s_setprio(1);
#pragma unroll
        for (int nt = 0; nt < 4; ++nt) {
            acc[0][nt] = __builtin_amdgcn_mfma_f32_16x16x32_f16(af0, bfh[nt], acc[0][nt], 0, 0, 0);
            acc[0][nt] = __builtin_amdgcn_mfma_f32_16x16x32_f16(af0, bfl[nt], acc[0][nt], 0, 0, 0);
        }
#pragma unroll
        for (int nt = 0; nt < 4; ++nt) {
            acc[1][nt] = __builtin_amdgcn_mfma_f32_16x16x32_f16(af1, bfh[nt], acc[1][nt], 0, 0, 0);
            acc[1][nt] = __builtin_amdgcn_mfma_f32_16x16x32_f16(af1, bfl[nt], acc[1][nt], 0, 0, 0);
        }
        __builtin_amdgcn_s_setprio(0);
    }
#undef ISSUE_DMA

    const float INV32 = 0.03125f;
    // ---------------- epilogue ----------------
    if (EPI == 0) {
#pragma unroll
        for (int nt = 0; nt < 4; ++nt) {
            const int n = n0 + nw + nt*16 + lx;
#pragma unroll
            for (int mt = 0; mt < 2; ++mt)
#pragma unroll
                for (int r = 0; r < 4; ++r) {
                    const int m = m0 + mw + mt*16 + quad*4 + r;
                    O0[(size_t)m*N + n] = acc[mt][nt][r]*INV32 + bias[n];
                }
        }
    } else {
        const int which = n0 >> 10;           // block-uniform: 0=q 1=k 2=v
        const int hbase = (n0 & 1023) >> 6;
        const int b     = m0 >> 11;
        const int t0    = m0 & 2047;
        float* Ct = (float*)smem;             // Q/K: [64][132]; V: [128][68]
        const float ssign = (lx & 1) ? 1.0f : -1.0f;

        __syncthreads();
        if (which < 2) {
#pragma unroll
            for (int nt = 0; nt < 4; ++nt) {
                const int nl = nw + nt*16 + lx;
                const int d  = nl & 63;
                const float bn = bias[n0 + nl];
                const float freq = expf(-(float)(d >> 1) * 0.28782313662425575f);
#pragma unroll
                for (int mt = 0; mt < 2; ++mt)
#pragma unroll
                    for (int r = 0; r < 4; ++r) {
                        const int ml = mw + mt*16 + quad*4 + r;
                        const int t  = t0 + ml;
                        float res = acc[mt][nt][r]*INV32 + bn;
                        const float ang = (float)t * freq;
                        const float sn = sinf(ang), cs = cosf(ang);
                        const float prt = __shfl_xor(res, 1);
                        res = res*cs + ssign*prt*sn;
                        // Q scale folds 1/sqrt(hd) AND log2(e): softmax in exp2 domain
                        if (which == 0) res *= 0.18033688011112042f;
                        Ct[ml*132 + nl] = res;
                    }
            }
        } else {
#pragma unroll
            for (int nt = 0; nt < 4; ++nt) {
                const int nl = nw + nt*16 + lx;
                const float bn = bias[n0 + nl];
#pragma unroll
                for (int mt = 0; mt < 2; ++mt)
#pragma unroll
                    for (int r = 0; r < 4; ++r) {
                        const int ml = mw + mt*16 + quad*4 + r;
                        Ct[nl*68 + ml] = acc[mt][nt][r]*INV32 + bn;
                    }
            }
        }
        __syncthreads();

        if (which < 2) {
#pragma unroll
            for (int u = 0; u < 4; ++u) {
                const int L  = u*32 + (tid >> 3);
                const int t  = L & 63;
                const int hl = L >> 6;
                const int dg = (tid & 7) * 8;
                const float* src = &Ct[t*132 + hl*64 + dg];
                float v[8];
                *(f32x4*)&v[0] = *(const f32x4*)src;
                *(f32x4*)&v[4] = *(const f32x4*)(src + 4);
                const int bh = b*NH + hbase + hl;
                const size_t off = (((size_t)bh)*T_SEQ + t0 + t)*64 + dg;
                s16x8 h8;
#pragma unroll
                for (int j = 0; j < 8; ++j) h8[j] = (short)f2h(v[j]);
                if (which == 0) {
                    *(s16x8*)&Qf[off] = h8;
                } else {
                    s16x8 l8;
#pragma unroll
                    for (int j = 0; j < 8; ++j)
                        l8[j] = (short)f2h(v[j] - h2f((ushort_t)h8[j]));
                    *(s16x8*)&Khf[off] = h8;
                    *(s16x8*)&Klf[off] = l8;
                }
            }
        } else {
#pragma unroll
            for (int u = 0; u < 4; ++u) {
                const int row = u*32 + (tid >> 3);
                const int d   = row & 63;
                const int hl  = row >> 6;
                const int tg  = (tid & 7) * 8;
                const float* src = &Ct[row*68 + tg];
                float v[8];
                *(f32x4*)&v[0] = *(const f32x4*)src;
                *(f32x4*)&v[4] = *(const f32x4*)(src + 4);
                s16x8 h8, l8;
#pragma unroll
                for (int j = 0; j < 8; ++j) {
                    h8[j] = (short)f2h(v[j]);
                    l8[j] = (short)f2h(v[j] - h2f((ushort_t)h8[j]));
                }
                const int bh = b*NH + hbase + hl;
                const size_t off = (((size_t)bh)*HD + d)*T_SEQ + t0 + tg;
                *(s16x8*)&Vthf[off] = h8;
                *(s16x8*)&Vtlf[off] = l8;
            }
        }
    }
}

// -------------------------------------------------------------------------
// Kernel 4: flash attention. R5: 4 waves x 32 q-rows (2 q-blocks/wave) --
// each K/V LDS fragment feeds 2 MFMAs -> LDS read traffic per MFMA halves
// (R4 diagnosis: LDS read pipe ~165us of 183us was the bottleneck).
// Same 1024-block grid, 256 threads, 32KB LDS, swapped-QK^T layout,
// fp16 2-product, mask as C-in, defer-max, setprio.
// -------------------------------------------------------------------------
__global__ __launch_bounds__(256, 3)
void attn_mfma_kernel(const ushort_t* __restrict__ Qf,
                      const ushort_t* __restrict__ Khf, const ushort_t* __restrict__ Klf,
                      const ushort_t* __restrict__ Vthf, const ushort_t* __restrict__ Vtlf,
                      const float* __restrict__ mbias,
                      ushort_t* __restrict__ AOf)
{
    __shared__ ushort_t KH[64*64];
    __shared__ ushort_t KL[64*64];
    __shared__ ushort_t VH[64*64];
    __shared__ ushort_t VL[64*64];

    const int tid  = threadIdx.x;
    const int w    = tid >> 6;          // 0..3
    const int ln   = tid & 63;
    const int lx   = ln & 15;
    const int quad = ln >> 4;

    // 1024 blocks: id&7 = bh low bits (XCD), (id>>3)&15 = qt, id>>7 = bh hi
    const int id = blockIdx.x;
    const int qt = (id >> 3) & 15;
    const int bh = ((id >> 7) << 3) | (id & 7);
    const int b  = bh >> 4;
    const int h  = bh & 15;
    const int qrow0 = qt*128 + w*32;

    // Q fragments (B operand, single fp16), 2 q-blocks of 16 rows
    f16x8 qf[2][2];
#pragma unroll
    for (int qb = 0; qb < 2; ++qb) {
        const size_t qo = (((size_t)bh)*T_SEQ + qrow0 + qb*16 + lx)*HD + quad*8;
        qf[qb][0] = *(const f16x8*)&Qf[qo];
        qf[qb][1] = *(const f16x8*)&Qf[qo + 32];
    }

    // staging: wave w stages rows [w*16, w*16+16) in two 8-row groups.
    // g(row) = (row&3) ^ (((row>>3)&1)<<2); rows w*16+j have g=j&3,
    // rows w*16+8+j have g=(j&3)^4.
    const int sj   = ln >> 3;           // 0..7
    const int sch  = ln & 7;
    const int srow = w*16 + sj;
    const size_t kg0 = ((size_t)bh*T_SEQ + srow)*HD + sch*8;
    const size_t vg0 = ((size_t)bh*HD + srow)*T_SEQ + sch*8;
    const int lw0 = srow*64 + ((sch ^ (sj & 3)) << 3);
    const int lw1 = (srow + 8)*64 + ((sch ^ (sj & 3) ^ 4) << 3);

    // K A-fragment read base: row(nt=0) = 8*(lx>>2)+(lx&3); g(row) == lx&7
    const int r0  = ((lx >> 2) << 3) + (lx & 3);
    const int ka0 = r0*64 + ((quad ^ (lx & 7)) << 3);
    // V B-fragment read base: row = nt*16+lx; g(row) == gv
    const int gv  = (lx & 3) ^ (((lx >> 3) & 1) << 2);
    const int va0 = lx*64 + ((quad ^ gv) << 3);

    // additive mask bias, float4 per nt: k = kt*64 +32*(nt>>1)+8*quad+4*(nt&1)+r
    const float* mrow = mbias + (size_t)b*T_SEQ + (quad << 3);

    f32x4 o[2][4];
#pragma unroll
    for (int qb = 0; qb < 2; ++qb)
#pragma unroll
        for (int nt = 0; nt < 4; ++nt) o[qb][nt] = (f32x4){0.f, 0.f, 0.f, 0.f};
    float mrun[2] = {-INFINITY, -INFINITY};
    float lrun[2] = {0.f, 0.f};

    s16x8 rkh0, rkh1, rkl0, rkl1, rvh0, rvh1, rvl0, rvl1;
    rkh0 = *(const s16x8*)&Khf [kg0];
    rkh1 = *(const s16x8*)&Khf [kg0 + (size_t)8*HD];
    rkl0 = *(const s16x8*)&Klf [kg0];
    rkl1 = *(const s16x8*)&Klf [kg0 + (size_t)8*HD];
    rvh0 = *(const s16x8*)&Vthf[vg0];
    rvh1 = *(const s16x8*)&Vthf[vg0 + (size_t)8*T_SEQ];
    rvl0 = *(const s16x8*)&Vtlf[vg0];
    rvl1 = *(const s16x8*)&Vtlf[vg0 + (size_t)8*T_SEQ];
    *(s16x8*)&KH[lw0] = rkh0;  *(s16x8*)&KH[lw1] = rkh1;
    *(s16x8*)&KL[lw0] = rkl0;  *(s16x8*)&KL[lw1] = rkl1;
    *(s16x8*)&VH[lw0] = rvh0;  *(s16x8*)&VH[lw1] = rvh1;
    *(s16x8*)&VL[lw0] = rvl0;  *(s16x8*)&VL[lw1] = rvl1;
    __syncthreads();

    for (int kt = 0; kt < T_SEQ/64; ++kt) {
        const int ktn = (kt+1 < T_SEQ/64) ? kt+1 : kt;
        const size_t kgt = kg0 + (size_t)ktn*64*HD;
        const size_t vgt = vg0 + ktn*64;
        rkh0 = *(const s16x8*)&Khf [kgt];
        rkh1 = *(const s16x8*)&Khf [kgt + (size_t)8*HD];
        rkl0 = *(const s16x8*)&Klf [kgt];
        rkl1 = *(const s16x8*)&Klf [kgt + (size_t)8*HD];
        rvh0 = *(const s16x8*)&Vthf[vgt];
        rvh1 = *(const s16x8*)&Vthf[vgt + (size_t)8*T_SEQ];
        rvl0 = *(const s16x8*)&Vtlf[vgt];
        rvl1 = *(const s16x8*)&Vtlf[vgt + (size_t)8*T_SEQ];

        // ---- QK^T (K split fp16 A operand; mask bias as C-in; 2 q-blocks) ----
        f32x4 s[2][4];
        __builtin_amdgcn_s_setprio(1);
#pragma unroll
        for (int nt = 0; nt < 4; ++nt) {
            const int a0 = ka0 + ((nt & 1) << 8) + ((nt >> 1) << 11);
            const f16x8 kh0 = *(const f16x8*)&KH[a0];
            const f16x8 kh1 = *(const f16x8*)&KH[a0 ^ 32];
            const f16x8 kl0 = *(const f16x8*)&KL[a0];
            const f16x8 kl1 = *(const f16x8*)&KL[a0 ^ 32];
            const f32x4 mb = *(const f32x4*)&mrow[kt*64 + ((nt >> 1) << 5) + ((nt & 1) << 2)];
            s[0][nt] = mb;
            s[1][nt] = mb;
            s[0][nt] = __builtin_amdgcn_mfma_f32_16x16x32_f16(kh0, qf[0][0], s[0][nt], 0, 0, 0);
            s[0][nt] = __builtin_amdgcn_mfma_f32_16x16x32_f16(kh1, qf[0][1], s[0][nt], 0, 0, 0);
            s[0][nt] = __builtin_amdgcn_mfma_f32_16x16x32_f16(kl0, qf[0][0], s[0][nt], 0, 0, 0);
            s[0][nt] = __builtin_amdgcn_mfma_f32_16x16x32_f16(kl1, qf[0][1], s[0][nt], 0, 0, 0);
            s[1][nt] = __builtin_amdgcn_mfma_f32_16x16x32_f16(kh0, qf[1][0], s[1][nt], 0, 0, 0);
            s[1][nt] = __builtin_amdgcn_mfma_f32_16x16x32_f16(kh1, qf[1][1], s[1][nt], 0, 0, 0);
            s[1][nt] = __builtin_amdgcn_mfma_f32_16x16x32_f16(kl0, qf[1][0], s[1][nt], 0, 0, 0);
            s[1][nt] = __builtin_amdgcn_mfma_f32_16x16x32_f16(kl1, qf[1][1], s[1][nt], 0, 0, 0);
        }
        __builtin_amdgcn_s_setprio(0);

        // ---- online softmax per q-block: row t=lx lane-local across quads ----
        float mt[2];
#pragma unroll
        for (int qb = 0; qb < 2; ++qb) {
            const float m0q = fmaxf(fmaxf(s[qb][0][0], s[qb][0][1]), fmaxf(s[qb][0][2], s[qb][0][3]));
            const float m1q = fmaxf(fmaxf(s[qb][1][0], s[qb][1][1]), fmaxf(s[qb][1][2], s[qb][1][3]));
            const float m2q = fmaxf(fmaxf(s[qb][2][0], s[qb][2][1]), fmaxf(s[qb][2][2], s[qb][2][3]));
            const float m3q = fmaxf(fmaxf(s[qb][3][0], s[qb][3][1]), fmaxf(s[qb][3][2], s[qb][3][3]));
            float m = fmaxf(fmaxf(m0q, m1q), fmaxf(m2q, m3q));
            m = fmaxf(m, __shfl_xor(m, 16));
            m = fmaxf(m, __shfl_xor(m, 32));
            mt[qb] = m;
        }

        // defer-max (T13): skip rescale while max growth <= 8 for BOTH blocks
        const bool stable = (mt[0] - mrun[0] <= 8.0f) && (mt[1] - mrun[1] <= 8.0f);
        if (!__all(stable)) {
#pragma unroll
            for (int qb = 0; qb < 2; ++qb) {
                const float mnew  = fmaxf(mrun[qb], mt[qb]);
                const float alpha = exp2_raw(mrun[qb] - mnew);
                mrun[qb] = mnew;
                lrun[qb] *= alpha;
                float ar[4];
#pragma unroll
                for (int r = 0; r < 4; ++r)
                    ar[r] = __shfl(alpha, (ln & 48) | ((quad << 2) + r));
#pragma unroll
                for (int nt = 0; nt < 4; ++nt)
#pragma unroll
                    for (int r = 0; r < 4; ++r) o[qb][nt][r] *= ar[r];
            }
        }

        union PU { unsigned u[4]; f16x8 v; };
        PU pf[2][2];
#pragma unroll
        for (int qb = 0; qb < 2; ++qb) {
            float lt = 0.f;
#pragma unroll
            for (int nt = 0; nt < 4; ++nt)
#pragma unroll
                for (int r = 0; r < 4; ++r) {
                    s[qb][nt][r] = exp2_raw(s[qb][nt][r] - mrun[qb]);
                    lt += s[qb][nt][r];
                }
            lt += __shfl_xor(lt, 16);
            lt += __shfl_xor(lt, 32);
            lrun[qb] += lt;

            // pack P -> single fp16 A-fragments (RNE), in-register
            unsigned pw[4][2];
#pragma unroll
            for (int nt = 0; nt < 4; ++nt) {
                pw[nt][0] = (unsigned)f2h(s[qb][nt][0]) | ((unsigned)f2h(s[qb][nt][1]) << 16);
                pw[nt][1] = (unsigned)f2h(s[qb][nt][2]) | ((unsigned)f2h(s[qb][nt][3]) << 16);
            }
            pf[qb][0].u[0] = pw[0][0]; pf[qb][0].u[1] = pw[0][1];
            pf[qb][0].u[2] = pw[1][0]; pf[qb][0].u[3] = pw[1][1];   // k 0..31
            pf[qb][1].u[0] = pw[2][0]; pf[qb][1].u[1] = pw[2][1];
            pf[qb][1].u[2] = pw[3][0]; pf[qb][1].u[3] = pw[3][1];   // k 32..63
        }

        // ---- PV (V split fp16 hi/lo; each V fragment feeds both q-blocks) ----
        __builtin_amdgcn_s_setprio(1);
#pragma unroll
        for (int nt = 0; nt < 4; ++nt) {
            const int v0 = va0 + (nt << 10);
            const f16x8 vh0 = *(const f16x8*)&VH[v0];
            const f16x8 vh1 = *(const f16x8*)&VH[v0 ^ 32];
            const f16x8 vl0 = *(const f16x8*)&VL[v0];
            const f16x8 vl1 = *(const f16x8*)&VL[v0 ^ 32];
            o[0][nt] = __builtin_amdgcn_mfma_f32_16x16x32_f16(pf[0][0].v, vh0, o[0][nt], 0, 0, 0);
            o[0][nt] = __builtin_amdgcn_mfma_f32_16x16x32_f16(pf[0][1].v, vh1, o[0][nt], 0, 0, 0);
            o[0][nt] = __builtin_amdgcn_mfma_f32_16x16x32_f16(pf[0][0].v, vl0, o[0][nt], 0, 0, 0);
            o[0][nt] = __builtin_amdgcn_mfma_f32_16x16x32_f16(pf[0][1].v, vl1, o[0][nt], 0, 0, 0);
            o[1][nt] = __builtin_amdgcn_mfma_f32_16x16x32_f16(pf[1][0].v, vh0, o[1][nt], 0, 0, 0);
            o[1][nt] = __builtin_amdgcn_mfma_f32_16x16x32_f16(pf[1][1].v, vh1, o[1][nt], 0, 0, 0);
            o[1][nt] = __builtin_amdgcn_mfma_f32_16x16x32_f16(pf[1][0].v, vl0, o[1][nt], 0, 0, 0);
            o[1][nt] = __builtin_amdgcn_mfma_f32_16x16x32_f16(pf[1][1].v, vl1, o[1][nt], 0, 0, 0);
        }
        __builtin_amdgcn_s_setprio(0);

        __syncthreads();
        *(s16x8*)&KH[lw0] = rkh0;  *(s16x8*)&KH[lw1] = rkh1;
        *(s16x8*)&KL[lw0] = rkl0;  *(s16x8*)&KL[lw1] = rkl1;
        *(s16x8*)&VH[lw0] = rvh0;  *(s16x8*)&VH[lw1] = rvh1;
        *(s16x8*)&VL[lw0] = rvl0;  *(s16x8*)&VL[lw1] = rvl1;
        __syncthreads();
    }

    // ---- normalize + single fp16 store to AOf[b][t][h*64+dv] ----
#pragma unroll
    for (int qb = 0; qb < 2; ++qb) {
        const float linv = 1.0f / lrun[qb];
        float ir[4];
#pragma unroll
        for (int r = 0; r < 4; ++r)
            ir[r] = __shfl(linv, (ln & 48) | ((quad << 2) + r));
#pragma unroll
        for (int nt = 0; nt < 4; ++nt)
#pragma unroll
            for (int r = 0; r < 4; ++r) {
                const int t = qrow0 + qb*16 + quad*4 + r;
                const float res = o[qb][nt][r] * ir[r];
                const size_t off = (((size_t)b)*T_SEQ + t)*DM + h*HD + nt*16 + lx;
                AOf[off] = f2h(res);
            }
    }
}

// -------------------------------------------------------------------------
// Memory plan: d_ws 128.03 MiB + d_out as scratch.
//   d_ws slots (16 MiB each): Qf | Khf | Klf | Vthf | Vtlf | (free) |
//         MSK 32 KiB | 32-MiB region R: WqkvTh/Tl (12 MiB, dead after
//         QKV GEMM) then AOf (16 MiB, attention output)
//   d_out: TokF (16 MiB) — dead after QKV GEMM
//   WoutTh/Tl <- Khf slot (dead after attention)
// -------------------------------------------------------------------------
extern "C" void kernel_launch(void* const* d_in, const int* in_sizes, int n_in,
                              void* d_out, int out_size, void* d_ws, size_t ws_size,
                              hipStream_t stream)
{
    const float* tokens = (const float*)d_in[0];
    const int*   pad    = (const int*)d_in[1];
    const float* Wqkv   = (const float*)d_in[2];
    const float* bqkv   = (const float*)d_in[3];
    const float* Wout   = (const float*)d_in[4];
    const float* bout   = (const float*)d_in[5];
    float* out = (float*)d_out;

    const size_t SZ = (size_t)8388608;
    ushort_t* U = (ushort_t*)d_ws;
    ushort_t* Qf   = U;
    ushort_t* Khf  = U + SZ;
    ushort_t* Klf  = U + 2*SZ;
    ushort_t* Vthf = U + 3*SZ;
    ushort_t* Vtlf = U + 4*SZ;
    float* MSK = (float*)(U + 6*SZ);
    ushort_t* R   = (ushort_t*)(MSK + 8192);       // 32-MiB region
    ushort_t* WqkvTh = R;
    ushort_t* WqkvTl = R + (size_t)3*DM*DM;
    ushort_t* AOf = R;                             // overlays dead WqkvT
    ushort_t* TokF = (ushort_t*)d_out;             // scratch in d_out
    ushort_t* WoutTh = Khf;                        // dead after attention
    ushort_t* WoutTl = Khf + (size_t)DM*DM;

    maskprep_kernel<<<dim3(BATCH), dim3(256), 0, stream>>>(pad, MSK);
    split_kernel<<<dim3(8192), dim3(256), 0, stream>>>(tokens, TokF);
    transpose_split_kernel<<<dim3(48, 16), dim3(256), 0, stream>>>(
        Wqkv, WqkvTh, WqkvTl, DM, 3*DM);
    mfma_gemm_kernel<1><<<dim3(24, 128), dim3(256), 0, stream>>>(
        TokF, WqkvTh, WqkvTl, bqkv, nullptr,
        Qf, Khf, Klf, Vthf, Vtlf, BATCH*T_SEQ, 3*DM, DM);
    attn_mfma_kernel<<<dim3(1024), dim3(256), 0, stream>>>(
        Qf, Khf, Klf, Vthf, Vtlf, MSK, AOf);
    transpose_split_kernel<<<dim3(16, 16), dim3(256), 0, stream>>>(
        Wout, WoutTh, WoutTl, DM, DM);
    mfma_gemm_kernel<0><<<dim3(8, 128), dim3(256), 0, stream>>>(
        AOf, WoutTh, WoutTl, bout, out,
        nullptr, nullptr, nullptr, nullptr, nullptr, BATCH*T_SEQ, DM, DM);
}

// Round 7
// 402.285 us; speedup vs baseline: 1.2216x; 1.2216x over previous
//
#include <hip/hip_runtime.h>
#include <cmath>

#define T_SEQ 2048
#define NH    16
#define HD    64
#define DM    1024
#define BATCH 4

typedef __attribute__((ext_vector_type(8))) short s16x8;
typedef __attribute__((ext_vector_type(8))) _Float16 f16x8;
typedef __attribute__((ext_vector_type(2))) __fp16 fp16v2;
typedef __attribute__((ext_vector_type(4))) float f32x4;
typedef unsigned short ushort_t;

__device__ __forceinline__ ushort_t f2h(float x) {   // rne fp32->fp16
    union { _Float16 h; ushort_t u; } v; v.h = (_Float16)x; return v.u;
}
__device__ __forceinline__ float h2f(ushort_t u) {
    union { ushort_t u; _Float16 h; } v; v.u = u; return (float)v.h;
}
// raw v_exp_f32 (2^x)
__device__ __forceinline__ float exp2_raw(float x) {
    return __builtin_amdgcn_exp2f(x);
}
// packed fp32x2 -> fp16x2 (RTZ), one instruction (v_cvt_pkrtz_f16_f32).
// NOTE: builtin returns __fp16 ext_vector(2) — union must match (R6 fail).
__device__ __forceinline__ unsigned pkrtz(float a, float b) {
    union { fp16v2 h; unsigned u; } v;
    v.h = __builtin_amdgcn_cvt_pkrtz(a, b);
    return v.u;
}

// async global->LDS DMA, 16 B per lane (verified R7/R9).
__device__ __forceinline__ void dma16(const void* g, const void* l) {
    __builtin_amdgcn_global_load_lds(
        (const __attribute__((address_space(1))) unsigned int*)(unsigned long long)g,
        (__attribute__((address_space(3))) unsigned int*)(unsigned int)(unsigned long long)l,
        16, 0, 0);
}

// -------------------------------------------------------------------------
// Kernel 1: mask prep. Emits ADDITIVE bias: 0.0 (attend) / -1e30 (pad).
// -------------------------------------------------------------------------
__global__ void maskprep_kernel(const int* __restrict__ pad, float* __restrict__ valid)
{
    __shared__ int sall[256];
    const int b = blockIdx.x;
    const int t = threadIdx.x;
    int allp = 1;
    for (int i = t; i < T_SEQ; i += 256) allp &= (pad[b*T_SEQ + i] != 0) ? 1 : 0;
    sall[t] = allp;
    __syncthreads();
    for (int s = 128; s > 0; s >>= 1) {
        if (t < s) sall[t] &= sall[t + s];
        __syncthreads();
    }
    const int ap = sall[0];
    for (int i = t; i < T_SEQ; i += 256) {
        const int p = (pad[b*T_SEQ + i] != 0) ? 1 : 0;
        valid[b*T_SEQ + i] = (p && !ap) ? -1e30f : 0.0f;
    }
}

// -------------------------------------------------------------------------
// Kernel 2: weight transpose+split. W[K][N] -> Th/Tl[N][K] as fp16 hi/lo
// of (32*w) — scaling keeps the lo part out of fp16 subnormal range.
// GEMM epilogue multiplies acc by 1/32.
// -------------------------------------------------------------------------
__global__ __launch_bounds__(256)
void transpose_split_kernel(const float* __restrict__ W,
                            ushort_t* __restrict__ Th, ushort_t* __restrict__ Tl,
                            int K, int N)
{
    __shared__ float T[64][68];
    const int tid = threadIdx.x;
    const int n0 = blockIdx.x * 64;
    const int k0 = blockIdx.y * 64;
#pragma unroll
    for (int i = 0; i < 4; ++i) {
        const int kr = (tid >> 4) + i*16;
        const int nc = (tid & 15) * 4;
        const float4 v = *(const float4*)&W[(size_t)(k0 + kr)*N + n0 + nc];
        T[nc+0][kr] = v.x; T[nc+1][kr] = v.y; T[nc+2][kr] = v.z; T[nc+3][kr] = v.w;
    }
    __syncthreads();
#pragma unroll
    for (int i = 0; i < 4; ++i) {
        const int nr = (tid >> 4) + i*16;
        const int kc = (tid & 15) * 4;
        ushort_t h[4], l[4];
#pragma unroll
        for (int j = 0; j < 4; ++j) {
            const float x = T[nr][kc + j] * 32.0f;
            h[j] = f2h(x);
            l[j] = f2h(x - h2f(h[j]));
        }
        const size_t off = (size_t)(n0 + nr)*K + k0 + kc;
        *(short4*)&Th[off] = make_short4((short)h[0], (short)h[1], (short)h[2], (short)h[3]);
        *(short4*)&Tl[off] = make_short4((short)l[0], (short)l[1], (short)l[2], (short)l[3]);
    }
}

// -------------------------------------------------------------------------
// Kernel 2b: row-major fp32 -> single fp16 (tokens).
// -------------------------------------------------------------------------
__global__ __launch_bounds__(256)
void split_kernel(const float* __restrict__ X, ushort_t* __restrict__ H)
{
    const int i = blockIdx.x * 256 + threadIdx.x;     // float4 index
    const float4 v = ((const float4*)X)[i];
    *(short4*)&H[(size_t)i*4] = make_short4(
        (short)f2h(v.x), (short)f2h(v.y), (short)f2h(v.z), (short)f2h(v.w));
}

// -------------------------------------------------------------------------
// Kernel 3/5: fp16 2-product MFMA GEMM. A = single fp16 activations,
// B = split fp16 hi/lo of 32*W. acc*(1/32)+bias in epilogue.
// R6: Q/K/V outputs are all SINGLE fp16 now (no lo arrays).
// -------------------------------------------------------------------------
template<int EPI>
__global__ __launch_bounds__(256)
void mfma_gemm_kernel(const ushort_t* __restrict__ Atf,
                      const ushort_t* __restrict__ BTh, const ushort_t* __restrict__ BTl,
                      const float* __restrict__ bias,
                      float* __restrict__ O0,
                      ushort_t* __restrict__ Qf,
                      ushort_t* __restrict__ Khf,
                      ushort_t* __restrict__ Vthf,
                      int M, int N, int K)
{
    __shared__ __align__(16) char smem[34816];
    char* smA  = smem;             // [64][32] fp16 = 4 KB
    char* smBh = smem + 4096;      // [128][32] fp16 = 8 KB
    char* smBl = smem + 12288;

    const int tid  = threadIdx.x;
    const int w    = tid >> 6;
    const int ln   = tid & 63;
    const int lx   = ln & 15;
    const int quad = ln >> 4;
    const int mw   = (w >> 1) * 32;
    const int nw   = (w & 1) * 64;
    const int m0   = blockIdx.y * 64;
    const int n0   = blockIdx.x * 128;

    const size_t gaA = (size_t)(m0 + w*16 + (ln >> 2))*K + (ln & 3)*8;
    const size_t gaB = (size_t)(n0 + w*32 + (ln >> 2))*K + (ln & 3)*8;
    const int ldsA = (w*64 + ln)*16;
    const int ldsB = (w*128 + ln)*16;

#define ISSUE_DMA(kk) do {                                               \
        dma16(Atf + gaA + (kk),        smA  + ldsA);                     \
        dma16(BTh + gaB + (kk),        smBh + ldsB);                     \
        dma16(BTh + gaB + 16*K + (kk), smBh + ldsB + 1024);              \
        dma16(BTl + gaB + (kk),        smBl + ldsB);                     \
        dma16(BTl + gaB + 16*K + (kk), smBl + ldsB + 1024);              \
    } while (0)

    f32x4 acc[2][4];
#pragma unroll
    for (int mt = 0; mt < 2; ++mt)
#pragma unroll
        for (int nt = 0; nt < 4; ++nt) acc[mt][nt] = (f32x4){0.f,0.f,0.f,0.f};

    ISSUE_DMA(0);

    for (int kk = 0; kk < K; kk += 32) {
        __syncthreads();

        f16x8 bfh[4], bfl[4];
#pragma unroll
        for (int nt = 0; nt < 4; ++nt) {
            const int off = (nw + nt*16 + lx)*64 + quad*16;
            bfh[nt] = *(const f16x8*)(smBh + off);
            bfl[nt] = *(const f16x8*)(smBl + off);
        }
        f16x8 af0, af1;
        {
            af0 = *(const f16x8*)(smA + (mw + lx)*64 + quad*16);
            af1 = *(const f16x8*)(smA + (mw + 16 + lx)*64 + quad*16);
        }
        __syncthreads();
        if (kk + 32 < K) ISSUE_DMA(kk + 32);

        __builtin_amdgcn_s_setprio(1);
#pragma unroll
        for (int nt = 0; nt < 4; ++nt) {
            acc[0][nt] = __builtin_amdgcn_mfma_f32_16x16x32_f16(af0, bfh[nt], acc[0][nt], 0, 0, 0);
            acc[0][nt] = __builtin_amdgcn_mfma_f32_16x16x32_f16(af0, bfl[nt], acc[0][nt], 0, 0, 0);
        }
#pragma unroll
        for (int nt = 0; nt < 4; ++nt) {
            acc[1][nt] = __builtin_amdgcn_mfma_f32_16x16x32_f16(af1, bfh[nt], acc[1][nt], 0, 0, 0);
            acc[1][nt] = __builtin_amdgcn_mfma_f32_16x16x32_f16(af1, bfl[nt], acc[1][nt], 0, 0, 0);
        }
        __builtin_amdgcn_s_setprio(0);
    }
#undef ISSUE_DMA

    const float INV32 = 0.03125f;
    // ---------------- epilogue ----------------
    if (EPI == 0) {
#pragma unroll
        for (int nt = 0; nt < 4; ++nt) {
            const int n = n0 + nw + nt*16 + lx;
#pragma unroll
            for (int mt = 0; mt < 2; ++mt)
#pragma unroll
                for (int r = 0; r < 4; ++r) {
                    const int m = m0 + mw + mt*16 + quad*4 + r;
                    O0[(size_t)m*N + n] = acc[mt][nt][r]*INV32 + bias[n];
                }
        }
    } else {
        const int which = n0 >> 10;           // block-uniform: 0=q 1=k 2=v
        const int hbase = (n0 & 1023) >> 6;
        const int b     = m0 >> 11;
        const int t0    = m0 & 2047;
        float* Ct = (float*)smem;             // Q/K: [64][132]; V: [128][68]
        const float ssign = (lx & 1) ? 1.0f : -1.0f;

        __syncthreads();
        if (which < 2) {
#pragma unroll
            for (int nt = 0; nt < 4; ++nt) {
                const int nl = nw + nt*16 + lx;
                const int d  = nl & 63;
                const float bn = bias[n0 + nl];
                const float freq = expf(-(float)(d >> 1) * 0.28782313662425575f);
#pragma unroll
                for (int mt = 0; mt < 2; ++mt)
#pragma unroll
                    for (int r = 0; r < 4; ++r) {
                        const int ml = mw + mt*16 + quad*4 + r;
                        const int t  = t0 + ml;
                        float res = acc[mt][nt][r]*INV32 + bn;
                        const float ang = (float)t * freq;
                        const float sn = sinf(ang), cs = cosf(ang);
                        const float prt = __shfl_xor(res, 1);
                        res = res*cs + ssign*prt*sn;
                        // Q scale folds 1/sqrt(hd) AND log2(e): softmax in exp2 domain
                        if (which == 0) res *= 0.18033688011112042f;
                        Ct[ml*132 + nl] = res;
                    }
            }
        } else {
#pragma unroll
            for (int nt = 0; nt < 4; ++nt) {
                const int nl = nw + nt*16 + lx;
                const float bn = bias[n0 + nl];
#pragma unroll
                for (int mt = 0; mt < 2; ++mt)
#pragma unroll
                    for (int r = 0; r < 4; ++r) {
                        const int ml = mw + mt*16 + quad*4 + r;
                        Ct[nl*68 + ml] = acc[mt][nt][r]*INV32 + bn;
                    }
            }
        }
        __syncthreads();

        if (which < 2) {
#pragma unroll
            for (int u = 0; u < 4; ++u) {
                const int L  = u*32 + (tid >> 3);
                const int t  = L & 63;
                const int hl = L >> 6;
                const int dg = (tid & 7) * 8;
                const float* src = &Ct[t*132 + hl*64 + dg];
                float v[8];
                *(f32x4*)&v[0] = *(const f32x4*)src;
                *(f32x4*)&v[4] = *(const f32x4*)(src + 4);
                s16x8 h8;
#pragma unroll
                for (int j = 0; j < 8; ++j) h8[j] = (short)f2h(v[j]);
                const int bh = b*NH + hbase + hl;
                const size_t off = (((size_t)bh)*T_SEQ + t0 + t)*64 + dg;
                if (which == 0) *(s16x8*)&Qf [off] = h8;
                else            *(s16x8*)&Khf[off] = h8;
            }
        } else {
#pragma unroll
            for (int u = 0; u < 4; ++u) {
                const int row = u*32 + (tid >> 3);
                const int d   = row & 63;
                const int hl  = row >> 6;
                const int tg  = (tid & 7) * 8;
                const float* src = &Ct[row*68 + tg];
                float v[8];
                *(f32x4*)&v[0] = *(const f32x4*)src;
                *(f32x4*)&v[4] = *(const f32x4*)(src + 4);
                s16x8 h8;
#pragma unroll
                for (int j = 0; j < 8; ++j) h8[j] = (short)f2h(v[j]);
                const int bh = b*NH + hbase + hl;
                const size_t off = (((size_t)bh)*HD + d)*T_SEQ + t0 + tg;
                *(s16x8*)&Vthf[off] = h8;
            }
        }
    }
}

// -------------------------------------------------------------------------
// Kernel 4: flash attention. R7 = R6 with pkrtz type fix. Pure fp16 K/V
// (no lo split) -> 32 MFMA per wave-tile (was 64), LDS 24 KB (KH 8 + VH 8
// + mask row 8). R5 post-mortem: kernel is phase-serialized (MfmaUtil+
// VALUBusy~74%, insensitive to LDS traffic); attack = shorten each phase.
// Mask row staged in LDS (broadcast ds_read C-in seed, removes ~200cy
// global latency from QK critical path). lt cross-quad reduce deferred
// to end. P packed via v_cvt_pkrtz (1 op / 2 vals).
// -------------------------------------------------------------------------
__global__ __launch_bounds__(256, 3)
void attn_mfma_kernel(const ushort_t* __restrict__ Qf,
                      const ushort_t* __restrict__ Khf,
                      const ushort_t* __restrict__ Vthf,
                      const float* __restrict__ mbias,
                      ushort_t* __restrict__ AOf)
{
    __shared__ ushort_t KH[64*64];    // 8 KB
    __shared__ ushort_t VH[64*64];    // 8 KB
    __shared__ float    MB[T_SEQ];    // 8 KB mask row for this batch

    const int tid  = threadIdx.x;
    const int w    = tid >> 6;          // 0..3
    const int ln   = tid & 63;
    const int lx   = ln & 15;
    const int quad = ln >> 4;

    // 1024 blocks: id&7 = bh low bits (XCD), (id>>3)&15 = qt, id>>7 = bh hi
    const int id = blockIdx.x;
    const int qt = (id >> 3) & 15;
    const int bh = ((id >> 7) << 3) | (id & 7);
    const int b  = bh >> 4;
    const int h  = bh & 15;
    const int qrow0 = qt*128 + w*32;

    // Q fragments (B operand, single fp16), 2 q-blocks of 16 rows
    f16x8 qf[2][2];
#pragma unroll
    for (int qb = 0; qb < 2; ++qb) {
        const size_t qo = (((size_t)bh)*T_SEQ + qrow0 + qb*16 + lx)*HD + quad*8;
        qf[qb][0] = *(const f16x8*)&Qf[qo];
        qf[qb][1] = *(const f16x8*)&Qf[qo + 32];
    }

    // mask row -> LDS (coalesced, once per block)
    {
        const f32x4* msrc = (const f32x4*)(mbias + (size_t)b*T_SEQ);
        f32x4* mdst = (f32x4*)MB;
#pragma unroll
        for (int i = 0; i < 2; ++i) mdst[tid + i*256] = msrc[tid + i*256];
    }

    // staging: wave w stages rows [w*16, w*16+16) in two 8-row groups.
    // g(row) = (row&3) ^ (((row>>3)&1)<<2)
    const int sj   = ln >> 3;           // 0..7
    const int sch  = ln & 7;
    const int srow = w*16 + sj;
    const size_t kg0 = ((size_t)bh*T_SEQ + srow)*HD + sch*8;
    const size_t vg0 = ((size_t)bh*HD + srow)*T_SEQ + sch*8;
    const int lw0 = srow*64 + ((sch ^ (sj & 3)) << 3);
    const int lw1 = (srow + 8)*64 + ((sch ^ (sj & 3) ^ 4) << 3);

    // K A-fragment read base: row(nt=0) = 8*(lx>>2)+(lx&3); g(row) == lx&7
    const int r0  = ((lx >> 2) << 3) + (lx & 3);
    const int ka0 = r0*64 + ((quad ^ (lx & 7)) << 3);
    // V B-fragment read base: row = nt*16+lx; g(row) == gv
    const int gv  = (lx & 3) ^ (((lx >> 3) & 1) << 2);
    const int va0 = lx*64 + ((quad ^ gv) << 3);

    f32x4 o[2][4];
#pragma unroll
    for (int qb = 0; qb < 2; ++qb)
#pragma unroll
        for (int nt = 0; nt < 4; ++nt) o[qb][nt] = (f32x4){0.f, 0.f, 0.f, 0.f};
    float mrun[2] = {-INFINITY, -INFINITY};
    float lrun[2] = {0.f, 0.f};        // per-lane PARTIAL sums (reduced at end)

    s16x8 rkh0, rkh1, rvh0, rvh1;
    rkh0 = *(const s16x8*)&Khf [kg0];
    rkh1 = *(const s16x8*)&Khf [kg0 + (size_t)8*HD];
    rvh0 = *(const s16x8*)&Vthf[vg0];
    rvh1 = *(const s16x8*)&Vthf[vg0 + (size_t)8*T_SEQ];
    *(s16x8*)&KH[lw0] = rkh0;  *(s16x8*)&KH[lw1] = rkh1;
    *(s16x8*)&VH[lw0] = rvh0;  *(s16x8*)&VH[lw1] = rvh1;
    __syncthreads();

    for (int kt = 0; kt < T_SEQ/64; ++kt) {
        const int ktn = (kt+1 < T_SEQ/64) ? kt+1 : kt;
        const size_t kgt = kg0 + (size_t)ktn*64*HD;
        const size_t vgt = vg0 + ktn*64;
        rkh0 = *(const s16x8*)&Khf [kgt];
        rkh1 = *(const s16x8*)&Khf [kgt + (size_t)8*HD];
        rvh0 = *(const s16x8*)&Vthf[vgt];
        rvh1 = *(const s16x8*)&Vthf[vgt + (size_t)8*T_SEQ];

        // mask C-in seeds from LDS (broadcast within each 16-lane quad group)
        f32x4 mb[4];
#pragma unroll
        for (int nt = 0; nt < 4; ++nt)
            mb[nt] = *(const f32x4*)&MB[kt*64 + (quad << 3) + ((nt >> 1) << 5) + ((nt & 1) << 2)];

        // ---- QK^T (single fp16 K as A operand; mask bias as C-in) ----
        f32x4 s[2][4];
        __builtin_amdgcn_s_setprio(1);
#pragma unroll
        for (int nt = 0; nt < 4; ++nt) {
            const int a0 = ka0 + ((nt & 1) << 8) + ((nt >> 1) << 11);
            const f16x8 kh0 = *(const f16x8*)&KH[a0];
            const f16x8 kh1 = *(const f16x8*)&KH[a0 ^ 32];
            s[0][nt] = mb[nt];
            s[1][nt] = mb[nt];
            s[0][nt] = __builtin_amdgcn_mfma_f32_16x16x32_f16(kh0, qf[0][0], s[0][nt], 0, 0, 0);
            s[0][nt] = __builtin_amdgcn_mfma_f32_16x16x32_f16(kh1, qf[0][1], s[0][nt], 0, 0, 0);
            s[1][nt] = __builtin_amdgcn_mfma_f32_16x16x32_f16(kh0, qf[1][0], s[1][nt], 0, 0, 0);
            s[1][nt] = __builtin_amdgcn_mfma_f32_16x16x32_f16(kh1, qf[1][1], s[1][nt], 0, 0, 0);
        }
        __builtin_amdgcn_s_setprio(0);

        // ---- online softmax per q-block: row t=lx lane-local across quads ----
        float mt[2];
#pragma unroll
        for (int qb = 0; qb < 2; ++qb) {
            const float m0q = fmaxf(fmaxf(s[qb][0][0], s[qb][0][1]), fmaxf(s[qb][0][2], s[qb][0][3]));
            const float m1q = fmaxf(fmaxf(s[qb][1][0], s[qb][1][1]), fmaxf(s[qb][1][2], s[qb][1][3]));
            const float m2q = fmaxf(fmaxf(s[qb][2][0], s[qb][2][1]), fmaxf(s[qb][2][2], s[qb][2][3]));
            const float m3q = fmaxf(fmaxf(s[qb][3][0], s[qb][3][1]), fmaxf(s[qb][3][2], s[qb][3][3]));
            float m = fmaxf(fmaxf(m0q, m1q), fmaxf(m2q, m3q));
            m = fmaxf(m, __shfl_xor(m, 16));
            m = fmaxf(m, __shfl_xor(m, 32));
            mt[qb] = m;
        }

        // defer-max (T13): skip rescale while max growth <= 8 for BOTH blocks
        const bool stable = (mt[0] - mrun[0] <= 8.0f) && (mt[1] - mrun[1] <= 8.0f);
        if (!__all(stable)) {
#pragma unroll
            for (int qb = 0; qb < 2; ++qb) {
                const float mnew  = fmaxf(mrun[qb], mt[qb]);
                const float alpha = exp2_raw(mrun[qb] - mnew);
                mrun[qb] = mnew;
                lrun[qb] *= alpha;      // partial sums scale by row-uniform alpha
                float ar[4];
#pragma unroll
                for (int r = 0; r < 4; ++r)
                    ar[r] = __shfl(alpha, (ln & 48) | ((quad << 2) + r));
#pragma unroll
                for (int nt = 0; nt < 4; ++nt)
#pragma unroll
                    for (int r = 0; r < 4; ++r) o[qb][nt][r] *= ar[r];
            }
        }

        union PU { unsigned u[4]; f16x8 v; };
        PU pf[2][2];
#pragma unroll
        for (int qb = 0; qb < 2; ++qb) {
            float lt = 0.f;
#pragma unroll
            for (int nt = 0; nt < 4; ++nt)
#pragma unroll
                for (int r = 0; r < 4; ++r) {
                    s[qb][nt][r] = exp2_raw(s[qb][nt][r] - mrun[qb]);
                    lt += s[qb][nt][r];
                }
            lrun[qb] += lt;             // per-lane partial; cross-quad at end

            // pack P -> fp16 A-fragments via v_cvt_pkrtz (1 op / 2 vals)
            pf[qb][0].u[0] = pkrtz(s[qb][0][0], s[qb][0][1]);
            pf[qb][0].u[1] = pkrtz(s[qb][0][2], s[qb][0][3]);
            pf[qb][0].u[2] = pkrtz(s[qb][1][0], s[qb][1][1]);
            pf[qb][0].u[3] = pkrtz(s[qb][1][2], s[qb][1][3]);   // k 0..31
            pf[qb][1].u[0] = pkrtz(s[qb][2][0], s[qb][2][1]);
            pf[qb][1].u[1] = pkrtz(s[qb][2][2], s[qb][2][3]);
            pf[qb][1].u[2] = pkrtz(s[qb][3][0], s[qb][3][1]);
            pf[qb][1].u[3] = pkrtz(s[qb][3][2], s[qb][3][3]);   // k 32..63
        }

        // ---- PV (single fp16 V; each V fragment feeds both q-blocks) ----
        __builtin_amdgcn_s_setprio(1);
#pragma unroll
        for (int nt = 0; nt < 4; ++nt) {
            const int v0 = va0 + (nt << 10);
            const f16x8 vh0 = *(const f16x8*)&VH[v0];
            const f16x8 vh1 = *(const f16x8*)&VH[v0 ^ 32];
            o[0][nt] = __builtin_amdgcn_mfma_f32_16x16x32_f16(pf[0][0].v, vh0, o[0][nt], 0, 0, 0);
            o[0][nt] = __builtin_amdgcn_mfma_f32_16x16x32_f16(pf[0][1].v, vh1, o[0][nt], 0, 0, 0);
            o[1][nt] = __builtin_amdgcn_mfma_f32_16x16x32_f16(pf[1][0].v, vh0, o[1][nt], 0, 0, 0);
            o[1][nt] = __builtin_amdgcn_mfma_f32_16x16x32_f16(pf[1][1].v, vh1, o[1][nt], 0, 0, 0);
        }
        __builtin_amdgcn_s_setprio(0);

        __syncthreads();
        *(s16x8*)&KH[lw0] = rkh0;  *(s16x8*)&KH[lw1] = rkh1;
        *(s16x8*)&VH[lw0] = rvh0;  *(s16x8*)&VH[lw1] = rvh1;
        __syncthreads();
    }

    // ---- final cross-quad l reduce + normalize + fp16 store ----
#pragma unroll
    for (int qb = 0; qb < 2; ++qb) {
        lrun[qb] += __shfl_xor(lrun[qb], 16);
        lrun[qb] += __shfl_xor(lrun[qb], 32);
        const float linv = 1.0f / lrun[qb];
        float ir[4];
#pragma unroll
        for (int r = 0; r < 4; ++r)
            ir[r] = __shfl(linv, (ln & 48) | ((quad << 2) + r));
#pragma unroll
        for (int nt = 0; nt < 4; ++nt)
#pragma unroll
            for (int r = 0; r < 4; ++r) {
                const int t = qrow0 + qb*16 + quad*4 + r;
                const float res = o[qb][nt][r] * ir[r];
                const size_t off = (((size_t)b)*T_SEQ + t)*DM + h*HD + nt*16 + lx;
                AOf[off] = f2h(res);
            }
    }
}

// -------------------------------------------------------------------------
// Memory plan: d_ws 128.03 MiB + d_out as scratch.
//   d_ws slots (16 MiB each): Qf | Khf | Vthf | (free x3) |
//         MSK 32 KiB | 32-MiB region R: WqkvTh/Tl (12 MiB, dead after
//         QKV GEMM) then AOf (16 MiB, attention output)
//   d_out: TokF (16 MiB) — dead after QKV GEMM
//   WoutTh/Tl <- Khf slot (dead after attention)
// -------------------------------------------------------------------------
extern "C" void kernel_launch(void* const* d_in, const int* in_sizes, int n_in,
                              void* d_out, int out_size, void* d_ws, size_t ws_size,
                              hipStream_t stream)
{
    const float* tokens = (const float*)d_in[0];
    const int*   pad    = (const int*)d_in[1];
    const float* Wqkv   = (const float*)d_in[2];
    const float* bqkv   = (const float*)d_in[3];
    const float* Wout   = (const float*)d_in[4];
    const float* bout   = (const float*)d_in[5];
    float* out = (float*)d_out;

    const size_t SZ = (size_t)8388608;
    ushort_t* U = (ushort_t*)d_ws;
    ushort_t* Qf   = U;
    ushort_t* Khf  = U + SZ;
    ushort_t* Vthf = U + 2*SZ;
    float* MSK = (float*)(U + 6*SZ);
    ushort_t* R   = (ushort_t*)(MSK + 8192);       // 32-MiB region
    ushort_t* WqkvTh = R;
    ushort_t* WqkvTl = R + (size_t)3*DM*DM;
    ushort_t* AOf = R;                             // overlays dead WqkvT
    ushort_t* TokF = (ushort_t*)d_out;             // scratch in d_out
    ushort_t* WoutTh = Khf;                        // dead after attention
    ushort_t* WoutTl = Khf + (size_t)DM*DM;

    maskprep_kernel<<<dim3(BATCH), dim3(256), 0, stream>>>(pad, MSK);
    split_kernel<<<dim3(8192), dim3(256), 0, stream>>>(tokens, TokF);
    transpose_split_kernel<<<dim3(48, 16), dim3(256), 0, stream>>>(
        Wqkv, WqkvTh, WqkvTl, DM, 3*DM);
    mfma_gemm_kernel<1><<<dim3(24, 128), dim3(256), 0, stream>>>(
        TokF, WqkvTh, WqkvTl, bqkv, nullptr,
        Qf, Khf, Vthf, BATCH*T_SEQ, 3*DM, DM);
    attn_mfma_kernel<<<dim3(1024), dim3(256), 0, stream>>>(
        Qf, Khf, Vthf, MSK, AOf);
    transpose_split_kernel<<<dim3(16, 16), dim3(256), 0, stream>>>(
        Wout, WoutTh, WoutTl, DM, DM);
    mfma_gemm_kernel<0><<<dim3(8, 128), dim3(256), 0, stream>>>(
        AOf, WoutTh, WoutTl, bout, out,
        nullptr, nullptr, nullptr, BATCH*T_SEQ, DM, DM);
}

// Round 8
// 393.538 us; speedup vs baseline: 1.2488x; 1.0222x over previous
//
#include <hip/hip_runtime.h>
#include <cmath>

#define T_SEQ 2048
#define NH    16
#define HD    64
#define DM    1024
#define BATCH 4

typedef __attribute__((ext_vector_type(8))) short s16x8;
typedef __attribute__((ext_vector_type(8))) _Float16 f16x8;
typedef __attribute__((ext_vector_type(2))) __fp16 fp16v2;
typedef __attribute__((ext_vector_type(4))) float f32x4;
typedef unsigned short ushort_t;

__device__ __forceinline__ ushort_t f2h(float x) {   // rne fp32->fp16
    union { _Float16 h; ushort_t u; } v; v.h = (_Float16)x; return v.u;
}
__device__ __forceinline__ float h2f(ushort_t u) {
    union { ushort_t u; _Float16 h; } v; v.u = u; return (float)v.h;
}
// raw v_exp_f32 (2^x)
__device__ __forceinline__ float exp2_raw(float x) {
    return __builtin_amdgcn_exp2f(x);
}
// packed fp32x2 -> fp16x2 (RTZ), one instruction (v_cvt_pkrtz_f16_f32).
// NOTE: builtin returns __fp16 ext_vector(2) — union must match (R6 fail).
__device__ __forceinline__ unsigned pkrtz(float a, float b) {
    union { fp16v2 h; unsigned u; } v;
    v.h = __builtin_amdgcn_cvt_pkrtz(a, b);
    return v.u;
}

// async global->LDS DMA, 16 B per lane (verified R7/R9).
__device__ __forceinline__ void dma16(const void* g, const void* l) {
    __builtin_amdgcn_global_load_lds(
        (const __attribute__((address_space(1))) unsigned int*)(unsigned long long)g,
        (__attribute__((address_space(3))) unsigned int*)(unsigned int)(unsigned long long)l,
        16, 0, 0);
}

// -------------------------------------------------------------------------
// Kernel 1: mask prep. Emits ADDITIVE bias: 0.0 (attend) / -1e30 (pad).
// -------------------------------------------------------------------------
__global__ void maskprep_kernel(const int* __restrict__ pad, float* __restrict__ valid)
{
    __shared__ int sall[256];
    const int b = blockIdx.x;
    const int t = threadIdx.x;
    int allp = 1;
    for (int i = t; i < T_SEQ; i += 256) allp &= (pad[b*T_SEQ + i] != 0) ? 1 : 0;
    sall[t] = allp;
    __syncthreads();
    for (int s = 128; s > 0; s >>= 1) {
        if (t < s) sall[t] &= sall[t + s];
        __syncthreads();
    }
    const int ap = sall[0];
    for (int i = t; i < T_SEQ; i += 256) {
        const int p = (pad[b*T_SEQ + i] != 0) ? 1 : 0;
        valid[b*T_SEQ + i] = (p && !ap) ? -1e30f : 0.0f;
    }
}

// -------------------------------------------------------------------------
// Kernel 2: weight transpose+split. W[K][N] -> Th/Tl[N][K] as fp16 hi/lo
// of (32*w) — scaling keeps the lo part out of fp16 subnormal range.
// GEMM epilogue multiplies acc by 1/32.
// -------------------------------------------------------------------------
__global__ __launch_bounds__(256)
void transpose_split_kernel(const float* __restrict__ W,
                            ushort_t* __restrict__ Th, ushort_t* __restrict__ Tl,
                            int K, int N)
{
    __shared__ float T[64][68];
    const int tid = threadIdx.x;
    const int n0 = blockIdx.x * 64;
    const int k0 = blockIdx.y * 64;
#pragma unroll
    for (int i = 0; i < 4; ++i) {
        const int kr = (tid >> 4) + i*16;
        const int nc = (tid & 15) * 4;
        const float4 v = *(const float4*)&W[(size_t)(k0 + kr)*N + n0 + nc];
        T[nc+0][kr] = v.x; T[nc+1][kr] = v.y; T[nc+2][kr] = v.z; T[nc+3][kr] = v.w;
    }
    __syncthreads();
#pragma unroll
    for (int i = 0; i < 4; ++i) {
        const int nr = (tid >> 4) + i*16;
        const int kc = (tid & 15) * 4;
        ushort_t h[4], l[4];
#pragma unroll
        for (int j = 0; j < 4; ++j) {
            const float x = T[nr][kc + j] * 32.0f;
            h[j] = f2h(x);
            l[j] = f2h(x - h2f(h[j]));
        }
        const size_t off = (size_t)(n0 + nr)*K + k0 + kc;
        *(short4*)&Th[off] = make_short4((short)h[0], (short)h[1], (short)h[2], (short)h[3]);
        *(short4*)&Tl[off] = make_short4((short)l[0], (short)l[1], (short)l[2], (short)l[3]);
    }
}

// -------------------------------------------------------------------------
// Kernel 2b: row-major fp32 -> single fp16 (tokens).
// -------------------------------------------------------------------------
__global__ __launch_bounds__(256)
void split_kernel(const float* __restrict__ X, ushort_t* __restrict__ H)
{
    const int i = blockIdx.x * 256 + threadIdx.x;     // float4 index
    const float4 v = ((const float4*)X)[i];
    *(short4*)&H[(size_t)i*4] = make_short4(
        (short)f2h(v.x), (short)f2h(v.y), (short)f2h(v.z), (short)f2h(v.w));
}

// -------------------------------------------------------------------------
// Kernel 3/5: fp16 2-product MFMA GEMM. A = single fp16 activations,
// B = split fp16 hi/lo of 32*W. acc*(1/32)+bias in epilogue.
// R8: LDS chunk swizzle c' = c ^ ((row>>1)&3) applied on BOTH sides
// (pre-swizzled global source for global_load_lds + swizzled ds_read) --
// R7 profile showed 1.6e7 bank conflicts (8-way on all fragment reads).
// Read set is now 64 distinct 16B slots per wave -> conflict-free.
// -------------------------------------------------------------------------
template<int EPI>
__global__ __launch_bounds__(256)
void mfma_gemm_kernel(const ushort_t* __restrict__ Atf,
                      const ushort_t* __restrict__ BTh, const ushort_t* __restrict__ BTl,
                      const float* __restrict__ bias,
                      float* __restrict__ O0,
                      ushort_t* __restrict__ Qf,
                      ushort_t* __restrict__ Khf,
                      ushort_t* __restrict__ Vthf,
                      int M, int N, int K)
{
    __shared__ __align__(16) char smem[34816];
    char* smA  = smem;             // [64][32] fp16 = 4 KB
    char* smBh = smem + 4096;      // [128][32] fp16 = 8 KB
    char* smBl = smem + 12288;

    const int tid  = threadIdx.x;
    const int w    = tid >> 6;
    const int ln   = tid & 63;
    const int lx   = ln & 15;
    const int quad = ln >> 4;
    const int mw   = (w >> 1) * 32;
    const int nw   = (w & 1) * 64;
    const int m0   = blockIdx.y * 64;
    const int n0   = blockIdx.x * 128;

    // staging: lane ln -> row base+(ln>>2), LDS chunk (ln&3) [linear dest].
    // source chunk pre-swizzled: (ln&3) ^ ((ln>>3)&3)  [= (row>>1)&3]
    const int swc = ((ln & 3) ^ ((ln >> 3) & 3)) * 8;
    const size_t gaA = (size_t)(m0 + w*16 + (ln >> 2))*K + swc;
    const size_t gaB = (size_t)(n0 + w*32 + (ln >> 2))*K + swc;
    const int ldsA = (w*64 + ln)*16;
    const int ldsB = (w*128 + ln)*16;

#define ISSUE_DMA(kk) do {                                               \
        dma16(Atf + gaA + (kk),        smA  + ldsA);                     \
        dma16(BTh + gaB + (kk),        smBh + ldsB);                     \
        dma16(BTh + gaB + 16*K + (kk), smBh + ldsB + 1024);              \
        dma16(BTl + gaB + (kk),        smBl + ldsB);                     \
        dma16(BTl + gaB + 16*K + (kk), smBl + ldsB + 1024);              \
    } while (0)

    f32x4 acc[2][4];
#pragma unroll
    for (int mt = 0; mt < 2; ++mt)
#pragma unroll
        for (int nt = 0; nt < 4; ++nt) acc[mt][nt] = (f32x4){0.f,0.f,0.f,0.f};

    ISSUE_DMA(0);

    // read-side swizzled chunk: (row>>1)&3 == (lx>>1)&3 for all fragments
    const int cs = (quad ^ ((lx >> 1) & 3)) * 16;

    for (int kk = 0; kk < K; kk += 32) {
        __syncthreads();

        f16x8 bfh[4], bfl[4];
#pragma unroll
        for (int nt = 0; nt < 4; ++nt) {
            const int off = (nw + nt*16 + lx)*64 + cs;
            bfh[nt] = *(const f16x8*)(smBh + off);
            bfl[nt] = *(const f16x8*)(smBl + off);
        }
        f16x8 af0, af1;
        {
            af0 = *(const f16x8*)(smA + (mw + lx)*64 + cs);
            af1 = *(const f16x8*)(smA + (mw + 16 + lx)*64 + cs);
        }
        __syncthreads();
        if (kk + 32 < K) ISSUE_DMA(kk + 32);

        __builtin_amdgcn_s_setprio(1);
#pragma unroll
        for (int nt = 0; nt < 4; ++nt) {
            acc[0][nt] = __builtin_amdgcn_mfma_f32_16x16x32_f16(af0, bfh[nt], acc[0][nt], 0, 0, 0);
            acc[0][nt] = __builtin_amdgcn_mfma_f32_16x16x32_f16(af0, bfl[nt], acc[0][nt], 0, 0, 0);
        }
#pragma unroll
        for (int nt = 0; nt < 4; ++nt) {
            acc[1][nt] = __builtin_amdgcn_mfma_f32_16x16x32_f16(af1, bfh[nt], acc[1][nt], 0, 0, 0);
            acc[1][nt] = __builtin_amdgcn_mfma_f32_16x16x32_f16(af1, bfl[nt], acc[1][nt], 0, 0, 0);
        }
        __builtin_amdgcn_s_setprio(0);
    }
#undef ISSUE_DMA

    const float INV32 = 0.03125f;
    // ---------------- epilogue ----------------
    if (EPI == 0) {
#pragma unroll
        for (int nt = 0; nt < 4; ++nt) {
            const int n = n0 + nw + nt*16 + lx;
#pragma unroll
            for (int mt = 0; mt < 2; ++mt)
#pragma unroll
                for (int r = 0; r < 4; ++r) {
                    const int m = m0 + mw + mt*16 + quad*4 + r;
                    O0[(size_t)m*N + n] = acc[mt][nt][r]*INV32 + bias[n];
                }
        }
    } else {
        const int which = n0 >> 10;           // block-uniform: 0=q 1=k 2=v
        const int hbase = (n0 & 1023) >> 6;
        const int b     = m0 >> 11;
        const int t0    = m0 & 2047;
        float* Ct = (float*)smem;             // Q/K: [64][132]; V: [128][68]
        const float ssign = (lx & 1) ? 1.0f : -1.0f;

        __syncthreads();
        if (which < 2) {
#pragma unroll
            for (int nt = 0; nt < 4; ++nt) {
                const int nl = nw + nt*16 + lx;
                const int d  = nl & 63;
                const float bn = bias[n0 + nl];
                const float freq = expf(-(float)(d >> 1) * 0.28782313662425575f);
#pragma unroll
                for (int mt = 0; mt < 2; ++mt)
#pragma unroll
                    for (int r = 0; r < 4; ++r) {
                        const int ml = mw + mt*16 + quad*4 + r;
                        const int t  = t0 + ml;
                        float res = acc[mt][nt][r]*INV32 + bn;
                        const float ang = (float)t * freq;
                        const float sn = sinf(ang), cs2 = cosf(ang);
                        const float prt = __shfl_xor(res, 1);
                        res = res*cs2 + ssign*prt*sn;
                        // Q scale folds 1/sqrt(hd) AND log2(e): softmax in exp2 domain
                        if (which == 0) res *= 0.18033688011112042f;
                        Ct[ml*132 + nl] = res;
                    }
            }
        } else {
#pragma unroll
            for (int nt = 0; nt < 4; ++nt) {
                const int nl = nw + nt*16 + lx;
                const float bn = bias[n0 + nl];
#pragma unroll
                for (int mt = 0; mt < 2; ++mt)
#pragma unroll
                    for (int r = 0; r < 4; ++r) {
                        const int ml = mw + mt*16 + quad*4 + r;
                        Ct[nl*68 + ml] = acc[mt][nt][r]*INV32 + bn;
                    }
            }
        }
        __syncthreads();

        if (which < 2) {
#pragma unroll
            for (int u = 0; u < 4; ++u) {
                const int L  = u*32 + (tid >> 3);
                const int t  = L & 63;
                const int hl = L >> 6;
                const int dg = (tid & 7) * 8;
                const float* src = &Ct[t*132 + hl*64 + dg];
                float v[8];
                *(f32x4*)&v[0] = *(const f32x4*)src;
                *(f32x4*)&v[4] = *(const f32x4*)(src + 4);
                s16x8 h8;
#pragma unroll
                for (int j = 0; j < 8; ++j) h8[j] = (short)f2h(v[j]);
                const int bh = b*NH + hbase + hl;
                const size_t off = (((size_t)bh)*T_SEQ + t0 + t)*64 + dg;
                if (which == 0) *(s16x8*)&Qf [off] = h8;
                else            *(s16x8*)&Khf[off] = h8;
            }
        } else {
#pragma unroll
            for (int u = 0; u < 4; ++u) {
                const int row = u*32 + (tid >> 3);
                const int d   = row & 63;
                const int hl  = row >> 6;
                const int tg  = (tid & 7) * 8;
                const float* src = &Ct[row*68 + tg];
                float v[8];
                *(f32x4*)&v[0] = *(const f32x4*)src;
                *(f32x4*)&v[4] = *(const f32x4*)(src + 4);
                s16x8 h8;
#pragma unroll
                for (int j = 0; j < 8; ++j) h8[j] = (short)f2h(v[j]);
                const int bh = b*NH + hbase + hl;
                const size_t off = (((size_t)bh)*HD + d)*T_SEQ + t0 + tg;
                *(s16x8*)&Vthf[off] = h8;
            }
        }
    }
}

// -------------------------------------------------------------------------
// Kernel 4: flash attention (R7 structure, unchanged). Pure fp16 K/V,
// 32 MFMA/wave-tile, LDS 24 KB, mask row in LDS, deferred l-reduce,
// pkrtz P pack, defer-max, setprio.
// -------------------------------------------------------------------------
__global__ __launch_bounds__(256, 3)
void attn_mfma_kernel(const ushort_t* __restrict__ Qf,
                      const ushort_t* __restrict__ Khf,
                      const ushort_t* __restrict__ Vthf,
                      const float* __restrict__ mbias,
                      ushort_t* __restrict__ AOf)
{
    __shared__ ushort_t KH[64*64];    // 8 KB
    __shared__ ushort_t VH[64*64];    // 8 KB
    __shared__ float    MB[T_SEQ];    // 8 KB mask row for this batch

    const int tid  = threadIdx.x;
    const int w    = tid >> 6;          // 0..3
    const int ln   = tid & 63;
    const int lx   = ln & 15;
    const int quad = ln >> 4;

    // 1024 blocks: id&7 = bh low bits (XCD), (id>>3)&15 = qt, id>>7 = bh hi
    const int id = blockIdx.x;
    const int qt = (id >> 3) & 15;
    const int bh = ((id >> 7) << 3) | (id & 7);
    const int b  = bh >> 4;
    const int h  = bh & 15;
    const int qrow0 = qt*128 + w*32;

    // Q fragments (B operand, single fp16), 2 q-blocks of 16 rows
    f16x8 qf[2][2];
#pragma unroll
    for (int qb = 0; qb < 2; ++qb) {
        const size_t qo = (((size_t)bh)*T_SEQ + qrow0 + qb*16 + lx)*HD + quad*8;
        qf[qb][0] = *(const f16x8*)&Qf[qo];
        qf[qb][1] = *(const f16x8*)&Qf[qo + 32];
    }

    // mask row -> LDS (coalesced, once per block)
    {
        const f32x4* msrc = (const f32x4*)(mbias + (size_t)b*T_SEQ);
        f32x4* mdst = (f32x4*)MB;
#pragma unroll
        for (int i = 0; i < 2; ++i) mdst[tid + i*256] = msrc[tid + i*256];
    }

    // staging: wave w stages rows [w*16, w*16+16) in two 8-row groups.
    // g(row) = (row&3) ^ (((row>>3)&1)<<2)
    const int sj   = ln >> 3;           // 0..7
    const int sch  = ln & 7;
    const int srow = w*16 + sj;
    const size_t kg0 = ((size_t)bh*T_SEQ + srow)*HD + sch*8;
    const size_t vg0 = ((size_t)bh*HD + srow)*T_SEQ + sch*8;
    const int lw0 = srow*64 + ((sch ^ (sj & 3)) << 3);
    const int lw1 = (srow + 8)*64 + ((sch ^ (sj & 3) ^ 4) << 3);

    // K A-fragment read base: row(nt=0) = 8*(lx>>2)+(lx&3); g(row) == lx&7
    const int r0  = ((lx >> 2) << 3) + (lx & 3);
    const int ka0 = r0*64 + ((quad ^ (lx & 7)) << 3);
    // V B-fragment read base: row = nt*16+lx; g(row) == gv
    const int gv  = (lx & 3) ^ (((lx >> 3) & 1) << 2);
    const int va0 = lx*64 + ((quad ^ gv) << 3);

    f32x4 o[2][4];
#pragma unroll
    for (int qb = 0; qb < 2; ++qb)
#pragma unroll
        for (int nt = 0; nt < 4; ++nt) o[qb][nt] = (f32x4){0.f, 0.f, 0.f, 0.f};
    float mrun[2] = {-INFINITY, -INFINITY};
    float lrun[2] = {0.f, 0.f};        // per-lane PARTIAL sums (reduced at end)

    s16x8 rkh0, rkh1, rvh0, rvh1;
    rkh0 = *(const s16x8*)&Khf [kg0];
    rkh1 = *(const s16x8*)&Khf [kg0 + (size_t)8*HD];
    rvh0 = *(const s16x8*)&Vthf[vg0];
    rvh1 = *(const s16x8*)&Vthf[vg0 + (size_t)8*T_SEQ];
    *(s16x8*)&KH[lw0] = rkh0;  *(s16x8*)&KH[lw1] = rkh1;
    *(s16x8*)&VH[lw0] = rvh0;  *(s16x8*)&VH[lw1] = rvh1;
    __syncthreads();

    for (int kt = 0; kt < T_SEQ/64; ++kt) {
        const int ktn = (kt+1 < T_SEQ/64) ? kt+1 : kt;
        const size_t kgt = kg0 + (size_t)ktn*64*HD;
        const size_t vgt = vg0 + ktn*64;
        rkh0 = *(const s16x8*)&Khf [kgt];
        rkh1 = *(const s16x8*)&Khf [kgt + (size_t)8*HD];
        rvh0 = *(const s16x8*)&Vthf[vgt];
        rvh1 = *(const s16x8*)&Vthf[vgt + (size_t)8*T_SEQ];

        // mask C-in seeds from LDS (broadcast within each 16-lane quad group)
        f32x4 mb[4];
#pragma unroll
        for (int nt = 0; nt < 4; ++nt)
            mb[nt] = *(const f32x4*)&MB[kt*64 + (quad << 3) + ((nt >> 1) << 5) + ((nt & 1) << 2)];

        // ---- QK^T (single fp16 K as A operand; mask bias as C-in) ----
        f32x4 s[2][4];
        __builtin_amdgcn_s_setprio(1);
#pragma unroll
        for (int nt = 0; nt < 4; ++nt) {
            const int a0 = ka0 + ((nt & 1) << 8) + ((nt >> 1) << 11);
            const f16x8 kh0 = *(const f16x8*)&KH[a0];
            const f16x8 kh1 = *(const f16x8*)&KH[a0 ^ 32];
            s[0][nt] = mb[nt];
            s[1][nt] = mb[nt];
            s[0][nt] = __builtin_amdgcn_mfma_f32_16x16x32_f16(kh0, qf[0][0], s[0][nt], 0, 0, 0);
            s[0][nt] = __builtin_amdgcn_mfma_f32_16x16x32_f16(kh1, qf[0][1], s[0][nt], 0, 0, 0);
            s[1][nt] = __builtin_amdgcn_mfma_f32_16x16x32_f16(kh0, qf[1][0], s[1][nt], 0, 0, 0);
            s[1][nt] = __builtin_amdgcn_mfma_f32_16x16x32_f16(kh1, qf[1][1], s[1][nt], 0, 0, 0);
        }
        __builtin_amdgcn_s_setprio(0);

        // ---- online softmax per q-block: row t=lx lane-local across quads ----
        float mt[2];
#pragma unroll
        for (int qb = 0; qb < 2; ++qb) {
            const float m0q = fmaxf(fmaxf(s[qb][0][0], s[qb][0][1]), fmaxf(s[qb][0][2], s[qb][0][3]));
            const float m1q = fmaxf(fmaxf(s[qb][1][0], s[qb][1][1]), fmaxf(s[qb][1][2], s[qb][1][3]));
            const float m2q = fmaxf(fmaxf(s[qb][2][0], s[qb][2][1]), fmaxf(s[qb][2][2], s[qb][2][3]));
            const float m3q = fmaxf(fmaxf(s[qb][3][0], s[qb][3][1]), fmaxf(s[qb][3][2], s[qb][3][3]));
            float m = fmaxf(fmaxf(m0q, m1q), fmaxf(m2q, m3q));
            m = fmaxf(m, __shfl_xor(m, 16));
            m = fmaxf(m, __shfl_xor(m, 32));
            mt[qb] = m;
        }

        // defer-max (T13): skip rescale while max growth <= 8 for BOTH blocks
        const bool stable = (mt[0] - mrun[0] <= 8.0f) && (mt[1] - mrun[1] <= 8.0f);
        if (!__all(stable)) {
#pragma unroll
            for (int qb = 0; qb < 2; ++qb) {
                const float mnew  = fmaxf(mrun[qb], mt[qb]);
                const float alpha = exp2_raw(mrun[qb] - mnew);
                mrun[qb] = mnew;
                lrun[qb] *= alpha;      // partial sums scale by row-uniform alpha
                float ar[4];
#pragma unroll
                for (int r = 0; r < 4; ++r)
                    ar[r] = __shfl(alpha, (ln & 48) | ((quad << 2) + r));
#pragma unroll
                for (int nt = 0; nt < 4; ++nt)
#pragma unroll
                    for (int r = 0; r < 4; ++r) o[qb][nt][r] *= ar[r];
            }
        }

        union PU { unsigned u[4]; f16x8 v; };
        PU pf[2][2];
#pragma unroll
        for (int qb = 0; qb < 2; ++qb) {
            float lt = 0.f;
#pragma unroll
            for (int nt = 0; nt < 4; ++nt)
#pragma unroll
                for (int r = 0; r < 4; ++r) {
                    s[qb][nt][r] = exp2_raw(s[qb][nt][r] - mrun[qb]);
                    lt += s[qb][nt][r];
                }
            lrun[qb] += lt;             // per-lane partial; cross-quad at end

            // pack P -> fp16 A-fragments via v_cvt_pkrtz (1 op / 2 vals)
            pf[qb][0].u[0] = pkrtz(s[qb][0][0], s[qb][0][1]);
            pf[qb][0].u[1] = pkrtz(s[qb][0][2], s[qb][0][3]);
            pf[qb][0].u[2] = pkrtz(s[qb][1][0], s[qb][1][1]);
            pf[qb][0].u[3] = pkrtz(s[qb][1][2], s[qb][1][3]);   // k 0..31
            pf[qb][1].u[0] = pkrtz(s[qb][2][0], s[qb][2][1]);
            pf[qb][1].u[1] = pkrtz(s[qb][2][2], s[qb][2][3]);
            pf[qb][1].u[2] = pkrtz(s[qb][3][0], s[qb][3][1]);
            pf[qb][1].u[3] = pkrtz(s[qb][3][2], s[qb][3][3]);   // k 32..63
        }

        // ---- PV (single fp16 V; each V fragment feeds both q-blocks) ----
        __builtin_amdgcn_s_setprio(1);
#pragma unroll
        for (int nt = 0; nt < 4; ++nt) {
            const int v0 = va0 + (nt << 10);
            const f16x8 vh0 = *(const f16x8*)&VH[v0];
            const f16x8 vh1 = *(const f16x8*)&VH[v0 ^ 32];
            o[0][nt] = __builtin_amdgcn_mfma_f32_16x16x32_f16(pf[0][0].v, vh0, o[0][nt], 0, 0, 0);
            o[0][nt] = __builtin_amdgcn_mfma_f32_16x16x32_f16(pf[0][1].v, vh1, o[0][nt], 0, 0, 0);
            o[1][nt] = __builtin_amdgcn_mfma_f32_16x16x32_f16(pf[1][0].v, vh0, o[1][nt], 0, 0, 0);
            o[1][nt] = __builtin_amdgcn_mfma_f32_16x16x32_f16(pf[1][1].v, vh1, o[1][nt], 0, 0, 0);
        }
        __builtin_amdgcn_s_setprio(0);

        __syncthreads();
        *(s16x8*)&KH[lw0] = rkh0;  *(s16x8*)&KH[lw1] = rkh1;
        *(s16x8*)&VH[lw0] = rvh0;  *(s16x8*)&VH[lw1] = rvh1;
        __syncthreads();
    }

    // ---- final cross-quad l reduce + normalize + fp16 store ----
#pragma unroll
    for (int qb = 0; qb < 2; ++qb) {
        lrun[qb] += __shfl_xor(lrun[qb], 16);
        lrun[qb] += __shfl_xor(lrun[qb], 32);
        const float linv = 1.0f / lrun[qb];
        float ir[4];
#pragma unroll
        for (int r = 0; r < 4; ++r)
            ir[r] = __shfl(linv, (ln & 48) | ((quad << 2) + r));
#pragma unroll
        for (int nt = 0; nt < 4; ++nt)
#pragma unroll
            for (int r = 0; r < 4; ++r) {
                const int t = qrow0 + qb*16 + quad*4 + r;
                const float res = o[qb][nt][r] * ir[r];
                const size_t off = (((size_t)b)*T_SEQ + t)*DM + h*HD + nt*16 + lx;
                AOf[off] = f2h(res);
            }
    }
}

// -------------------------------------------------------------------------
// Memory plan: d_ws 128.03 MiB + d_out as scratch.
//   d_ws slots (16 MiB each): Qf | Khf | Vthf | (free x3) |
//         MSK 32 KiB | 32-MiB region R: WqkvTh/Tl (12 MiB, dead after
//         QKV GEMM) then AOf (16 MiB, attention output)
//   d_out: TokF (16 MiB) — dead after QKV GEMM
//   WoutTh/Tl <- Khf slot (dead after attention)
// -------------------------------------------------------------------------
extern "C" void kernel_launch(void* const* d_in, const int* in_sizes, int n_in,
                              void* d_out, int out_size, void* d_ws, size_t ws_size,
                              hipStream_t stream)
{
    const float* tokens = (const float*)d_in[0];
    const int*   pad    = (const int*)d_in[1];
    const float* Wqkv   = (const float*)d_in[2];
    const float* bqkv   = (const float*)d_in[3];
    const float* Wout   = (const float*)d_in[4];
    const float* bout   = (const float*)d_in[5];
    float* out = (float*)d_out;

    const size_t SZ = (size_t)8388608;
    ushort_t* U = (ushort_t*)d_ws;
    ushort_t* Qf   = U;
    ushort_t* Khf  = U + SZ;
    ushort_t* Vthf = U + 2*SZ;
    float* MSK = (float*)(U + 6*SZ);
    ushort_t* R   = (ushort_t*)(MSK + 8192);       // 32-MiB region
    ushort_t* WqkvTh = R;
    ushort_t* WqkvTl = R + (size_t)3*DM*DM;
    ushort_t* AOf = R;                             // overlays dead WqkvT
    ushort_t* TokF = (ushort_t*)d_out;             // scratch in d_out
    ushort_t* WoutTh = Khf;                        // dead after attention
    ushort_t* WoutTl = Khf + (size_t)DM*DM;

    maskprep_kernel<<<dim3(BATCH), dim3(256), 0, stream>>>(pad, MSK);
    split_kernel<<<dim3(8192), dim3(256), 0, stream>>>(tokens, TokF);
    transpose_split_kernel<<<dim3(48, 16), dim3(256), 0, stream>>>(
        Wqkv, WqkvTh, WqkvTl, DM, 3*DM);
    mfma_gemm_kernel<1><<<dim3(24, 128), dim3(256), 0, stream>>>(
        TokF, WqkvTh, WqkvTl, bqkv, nullptr,
        Qf, Khf, Vthf, BATCH*T_SEQ, 3*DM, DM);
    attn_mfma_kernel<<<dim3(1024), dim3(256), 0, stream>>>(
        Qf, Khf, Vthf, MSK, AOf);
    transpose_split_kernel<<<dim3(16, 16), dim3(256), 0, stream>>>(
        Wout, WoutTh, WoutTl, DM, DM);
    mfma_gemm_kernel<0><<<dim3(8, 128), dim3(256), 0, stream>>>(
        AOf, WoutTh, WoutTl, bout, out,
        nullptr, nullptr, nullptr, BATCH*T_SEQ, DM, DM);
}

// Round 9
// 331.374 us; speedup vs baseline: 1.4830x; 1.1876x over previous
//
#include <hip/hip_runtime.h>
#include <cmath>

#define T_SEQ 2048
#define NH    16
#define HD    64
#define DM    1024
#define BATCH 4

typedef __attribute__((ext_vector_type(8))) short s16x8;
typedef __attribute__((ext_vector_type(8))) _Float16 f16x8;
typedef __attribute__((ext_vector_type(2))) __fp16 fp16v2;
typedef __attribute__((ext_vector_type(4))) float f32x4;
typedef unsigned short ushort_t;

__device__ __forceinline__ ushort_t f2h(float x) {   // rne fp32->fp16
    union { _Float16 h; ushort_t u; } v; v.h = (_Float16)x; return v.u;
}
__device__ __forceinline__ float h2f(ushort_t u) {
    union { ushort_t u; _Float16 h; } v; v.u = u; return (float)v.h;
}
// raw v_exp_f32 (2^x)
__device__ __forceinline__ float exp2_raw(float x) {
    return __builtin_amdgcn_exp2f(x);
}
// packed fp32x2 -> fp16x2 (RTZ), one instruction (v_cvt_pkrtz_f16_f32).
// NOTE: builtin returns __fp16 ext_vector(2) — union must match (R6 fail).
__device__ __forceinline__ unsigned pkrtz(float a, float b) {
    union { fp16v2 h; unsigned u; } v;
    v.h = __builtin_amdgcn_cvt_pkrtz(a, b);
    return v.u;
}

// async global->LDS DMA, 16 B per lane (verified R7/R9).
__device__ __forceinline__ void dma16(const void* g, const void* l) {
    __builtin_amdgcn_global_load_lds(
        (const __attribute__((address_space(1))) unsigned int*)(unsigned long long)g,
        (__attribute__((address_space(3))) unsigned int*)(unsigned int)(unsigned long long)l,
        16, 0, 0);
}

// -------------------------------------------------------------------------
// Kernel 1: mask prep. Emits ADDITIVE bias: 0.0 (attend) / -1e30 (pad).
// -------------------------------------------------------------------------
__global__ void maskprep_kernel(const int* __restrict__ pad, float* __restrict__ valid)
{
    __shared__ int sall[256];
    const int b = blockIdx.x;
    const int t = threadIdx.x;
    int allp = 1;
    for (int i = t; i < T_SEQ; i += 256) allp &= (pad[b*T_SEQ + i] != 0) ? 1 : 0;
    sall[t] = allp;
    __syncthreads();
    for (int s = 128; s > 0; s >>= 1) {
        if (t < s) sall[t] &= sall[t + s];
        __syncthreads();
    }
    const int ap = sall[0];
    for (int i = t; i < T_SEQ; i += 256) {
        const int p = (pad[b*T_SEQ + i] != 0) ? 1 : 0;
        valid[b*T_SEQ + i] = (p && !ap) ? -1e30f : 0.0f;
    }
}

// -------------------------------------------------------------------------
// Kernel 2: weight transpose. W[K][N] -> Th[N][K] as SINGLE fp16 of (32*w)
// (R9: hi/lo split dropped; x32 scaling keeps small weights well inside
// fp16 normal range). GEMM epilogue multiplies acc by 1/32.
// -------------------------------------------------------------------------
__global__ __launch_bounds__(256)
void transpose_h_kernel(const float* __restrict__ W,
                        ushort_t* __restrict__ Th, int K, int N)
{
    __shared__ float T[64][68];
    const int tid = threadIdx.x;
    const int n0 = blockIdx.x * 64;
    const int k0 = blockIdx.y * 64;
#pragma unroll
    for (int i = 0; i < 4; ++i) {
        const int kr = (tid >> 4) + i*16;
        const int nc = (tid & 15) * 4;
        const float4 v = *(const float4*)&W[(size_t)(k0 + kr)*N + n0 + nc];
        T[nc+0][kr] = v.x; T[nc+1][kr] = v.y; T[nc+2][kr] = v.z; T[nc+3][kr] = v.w;
    }
    __syncthreads();
#pragma unroll
    for (int i = 0; i < 4; ++i) {
        const int nr = (tid >> 4) + i*16;
        const int kc = (tid & 15) * 4;
        ushort_t h[4];
#pragma unroll
        for (int j = 0; j < 4; ++j) h[j] = f2h(T[nr][kc + j] * 32.0f);
        const size_t off = (size_t)(n0 + nr)*K + k0 + kc;
        *(short4*)&Th[off] = make_short4((short)h[0], (short)h[1], (short)h[2], (short)h[3]);
    }
}

// -------------------------------------------------------------------------
// Kernel 2b: row-major fp32 -> single fp16 (tokens).
// -------------------------------------------------------------------------
__global__ __launch_bounds__(256)
void split_kernel(const float* __restrict__ X, ushort_t* __restrict__ H)
{
    const int i = blockIdx.x * 256 + threadIdx.x;     // float4 index
    const float4 v = ((const float4*)X)[i];
    *(short4*)&H[(size_t)i*4] = make_short4(
        (short)f2h(v.x), (short)f2h(v.y), (short)f2h(v.z), (short)f2h(v.w));
}

// -------------------------------------------------------------------------
// Kernel 3/5: single-fp16 MFMA GEMM, double-buffered LDS, ONE barrier per
// K-step (R9). A = fp16 activations, B = fp16 (32*W)^T. acc*(1/32)+bias.
// Prefetch for step k+1 is issued at the TOP of step k into the idle
// buffer; the compiler's vmcnt(0)-before-barrier at end of step drains it
// (overlap window = full step, vs MFMA-only in the R8 2-barrier loop).
// R8's both-sides chunk swizzle retained (conflict-free reads).
// -------------------------------------------------------------------------
template<int EPI>
__global__ __launch_bounds__(256)
void mfma_gemm_kernel(const ushort_t* __restrict__ Atf,
                      const ushort_t* __restrict__ BTh,
                      const float* __restrict__ bias,
                      float* __restrict__ O0,
                      ushort_t* __restrict__ Qf,
                      ushort_t* __restrict__ Khf,
                      ushort_t* __restrict__ Vthf,
                      int M, int N, int K)
{
    __shared__ __align__(16) char smem[34816];
    char* smA0 = smem;             // [64][32] fp16 = 4 KB
    char* smA1 = smem + 4096;
    char* smB0 = smem + 8192;      // [128][32] fp16 = 8 KB
    char* smB1 = smem + 16384;     // K-loop uses 24 KB; epilogue overlays

    const int tid  = threadIdx.x;
    const int w    = tid >> 6;
    const int ln   = tid & 63;
    const int lx   = ln & 15;
    const int quad = ln >> 4;
    const int mw   = (w >> 1) * 32;
    const int nw   = (w & 1) * 64;
    const int m0   = blockIdx.y * 64;
    const int n0   = blockIdx.x * 128;

    // staging: lane ln -> row base+(ln>>2), LDS chunk ln&3 [linear dest].
    // source chunk pre-swizzled: (ln&3) ^ ((ln>>3)&3)  [= (row>>1)&3]
    const int swc = ((ln & 3) ^ ((ln >> 3) & 3)) * 8;
    const size_t gaA = (size_t)(m0 + w*16 + (ln >> 2))*K + swc;
    const size_t gaB = (size_t)(n0 + w*32 + (ln >> 2))*K + swc;
    const int ldsA = (w*64 + ln)*16;
    const int ldsB = (w*128 + ln)*16;

#define ISSUE_DMA(kk, dA, dB) do {                                       \
        dma16(Atf + gaA + (kk),        (dA) + ldsA);                     \
        dma16(BTh + gaB + (kk),        (dB) + ldsB);                     \
        dma16(BTh + gaB + 16*K + (kk), (dB) + ldsB + 1024);              \
    } while (0)

    f32x4 acc[2][4];
#pragma unroll
    for (int mt = 0; mt < 2; ++mt)
#pragma unroll
        for (int nt = 0; nt < 4; ++nt) acc[mt][nt] = (f32x4){0.f,0.f,0.f,0.f};

    // read-side swizzled chunk: (row>>1)&3 == (lx>>1)&3 for all fragments
    const int cs = (quad ^ ((lx >> 1) & 3)) * 16;

#define GEMM_STEP(kk, cA, cB, nA, nB) do {                                \
        if ((kk) + 32 < K) ISSUE_DMA((kk) + 32, nA, nB);                  \
        f16x8 bfh[4];                                                     \
        _Pragma("unroll")                                                 \
        for (int nt = 0; nt < 4; ++nt)                                    \
            bfh[nt] = *(const f16x8*)((cB) + (nw + nt*16 + lx)*64 + cs);  \
        const f16x8 af0 = *(const f16x8*)((cA) + (mw + lx)*64 + cs);      \
        const f16x8 af1 = *(const f16x8*)((cA) + (mw + 16 + lx)*64 + cs); \
        __builtin_amdgcn_s_setprio(1);                                    \
        _Pragma("unroll")                                                 \
        for (int nt = 0; nt < 4; ++nt) {                                  \
            acc[0][nt] = __builtin_amdgcn_mfma_f32_16x16x32_f16(af0, bfh[nt], acc[0][nt], 0, 0, 0); \
            acc[1][nt] = __builtin_amdgcn_mfma_f32_16x16x32_f16(af1, bfh[nt], acc[1][nt], 0, 0, 0); \
        }                                                                 \
        __builtin_amdgcn_s_setprio(0);                                    \
        __syncthreads();                                                  \
    } while (0)

    ISSUE_DMA(0, smA0, smB0);
    __syncthreads();
    for (int kk = 0; kk < K; kk += 64) {
        GEMM_STEP(kk,      smA0, smB0, smA1, smB1);
        GEMM_STEP(kk + 32, smA1, smB1, smA0, smB0);
    }
#undef GEMM_STEP
#undef ISSUE_DMA

    const float INV32 = 0.03125f;
    // ---------------- epilogue ----------------
    if (EPI == 0) {
#pragma unroll
        for (int nt = 0; nt < 4; ++nt) {
            const int n = n0 + nw + nt*16 + lx;
#pragma unroll
            for (int mt = 0; mt < 2; ++mt)
#pragma unroll
                for (int r = 0; r < 4; ++r) {
                    const int m = m0 + mw + mt*16 + quad*4 + r;
                    O0[(size_t)m*N + n] = acc[mt][nt][r]*INV32 + bias[n];
                }
        }
    } else {
        const int which = n0 >> 10;           // block-uniform: 0=q 1=k 2=v
        const int hbase = (n0 & 1023) >> 6;
        const int b     = m0 >> 11;
        const int t0    = m0 & 2047;
        float* Ct = (float*)smem;             // Q/K: [64][132]; V: [128][68]
        const float ssign = (lx & 1) ? 1.0f : -1.0f;

        __syncthreads();
        if (which < 2) {
#pragma unroll
            for (int nt = 0; nt < 4; ++nt) {
                const int nl = nw + nt*16 + lx;
                const int d  = nl & 63;
                const float bn = bias[n0 + nl];
                const float freq = expf(-(float)(d >> 1) * 0.28782313662425575f);
#pragma unroll
                for (int mt = 0; mt < 2; ++mt)
#pragma unroll
                    for (int r = 0; r < 4; ++r) {
                        const int ml = mw + mt*16 + quad*4 + r;
                        const int t  = t0 + ml;
                        float res = acc[mt][nt][r]*INV32 + bn;
                        const float ang = (float)t * freq;
                        const float sn = sinf(ang), cs2 = cosf(ang);
                        const float prt = __shfl_xor(res, 1);
                        res = res*cs2 + ssign*prt*sn;
                        // Q scale folds 1/sqrt(hd) AND log2(e): softmax in exp2 domain
                        if (which == 0) res *= 0.18033688011112042f;
                        Ct[ml*132 + nl] = res;
                    }
            }
        } else {
#pragma unroll
            for (int nt = 0; nt < 4; ++nt) {
                const int nl = nw + nt*16 + lx;
                const float bn = bias[n0 + nl];
#pragma unroll
                for (int mt = 0; mt < 2; ++mt)
#pragma unroll
                    for (int r = 0; r < 4; ++r) {
                        const int ml = mw + mt*16 + quad*4 + r;
                        Ct[nl*68 + ml] = acc[mt][nt][r]*INV32 + bn;
                    }
            }
        }
        __syncthreads();

        if (which < 2) {
#pragma unroll
            for (int u = 0; u < 4; ++u) {
                const int L  = u*32 + (tid >> 3);
                const int t  = L & 63;
                const int hl = L >> 6;
                const int dg = (tid & 7) * 8;
                const float* src = &Ct[t*132 + hl*64 + dg];
                float v[8];
                *(f32x4*)&v[0] = *(const f32x4*)src;
                *(f32x4*)&v[4] = *(const f32x4*)(src + 4);
                s16x8 h8;
#pragma unroll
                for (int j = 0; j < 8; ++j) h8[j] = (short)f2h(v[j]);
                const int bh = b*NH + hbase + hl;
                const size_t off = (((size_t)bh)*T_SEQ + t0 + t)*64 + dg;
                if (which == 0) *(s16x8*)&Qf [off] = h8;
                else            *(s16x8*)&Khf[off] = h8;
            }
        } else {
#pragma unroll
            for (int u = 0; u < 4; ++u) {
                const int row = u*32 + (tid >> 3);
                const int d   = row & 63;
                const int hl  = row >> 6;
                const int tg  = (tid & 7) * 8;
                const float* src = &Ct[row*68 + tg];
                float v[8];
                *(f32x4*)&v[0] = *(const f32x4*)src;
                *(f32x4*)&v[4] = *(const f32x4*)(src + 4);
                s16x8 h8;
#pragma unroll
                for (int j = 0; j < 8; ++j) h8[j] = (short)f2h(v[j]);
                const int bh = b*NH + hbase + hl;
                const size_t off = (((size_t)bh)*HD + d)*T_SEQ + t0 + tg;
                *(s16x8*)&Vthf[off] = h8;
            }
        }
    }
}

// -------------------------------------------------------------------------
// Kernel 4: flash attention (R7 structure, unchanged). Pure fp16 K/V,
// 32 MFMA/wave-tile, LDS 24 KB, mask row in LDS, deferred l-reduce,
// pkrtz P pack, defer-max, setprio.
// -------------------------------------------------------------------------
__global__ __launch_bounds__(256, 3)
void attn_mfma_kernel(const ushort_t* __restrict__ Qf,
                      const ushort_t* __restrict__ Khf,
                      const ushort_t* __restrict__ Vthf,
                      const float* __restrict__ mbias,
                      ushort_t* __restrict__ AOf)
{
    __shared__ ushort_t KH[64*64];    // 8 KB
    __shared__ ushort_t VH[64*64];    // 8 KB
    __shared__ float    MB[T_SEQ];    // 8 KB mask row for this batch

    const int tid  = threadIdx.x;
    const int w    = tid >> 6;          // 0..3
    const int ln   = tid & 63;
    const int lx   = ln & 15;
    const int quad = ln >> 4;

    // 1024 blocks: id&7 = bh low bits (XCD), (id>>3)&15 = qt, id>>7 = bh hi
    const int id = blockIdx.x;
    const int qt = (id >> 3) & 15;
    const int bh = ((id >> 7) << 3) | (id & 7);
    const int b  = bh >> 4;
    const int h  = bh & 15;
    const int qrow0 = qt*128 + w*32;

    // Q fragments (B operand, single fp16), 2 q-blocks of 16 rows
    f16x8 qf[2][2];
#pragma unroll
    for (int qb = 0; qb < 2; ++qb) {
        const size_t qo = (((size_t)bh)*T_SEQ + qrow0 + qb*16 + lx)*HD + quad*8;
        qf[qb][0] = *(const f16x8*)&Qf[qo];
        qf[qb][1] = *(const f16x8*)&Qf[qo + 32];
    }

    // mask row -> LDS (coalesced, once per block)
    {
        const f32x4* msrc = (const f32x4*)(mbias + (size_t)b*T_SEQ);
        f32x4* mdst = (f32x4*)MB;
#pragma unroll
        for (int i = 0; i < 2; ++i) mdst[tid + i*256] = msrc[tid + i*256];
    }

    // staging: wave w stages rows [w*16, w*16+16) in two 8-row groups.
    // g(row) = (row&3) ^ (((row>>3)&1)<<2)
    const int sj   = ln >> 3;           // 0..7
    const int sch  = ln & 7;
    const int srow = w*16 + sj;
    const size_t kg0 = ((size_t)bh*T_SEQ + srow)*HD + sch*8;
    const size_t vg0 = ((size_t)bh*HD + srow)*T_SEQ + sch*8;
    const int lw0 = srow*64 + ((sch ^ (sj & 3)) << 3);
    const int lw1 = (srow + 8)*64 + ((sch ^ (sj & 3) ^ 4) << 3);

    // K A-fragment read base: row(nt=0) = 8*(lx>>2)+(lx&3); g(row) == lx&7
    const int r0  = ((lx >> 2) << 3) + (lx & 3);
    const int ka0 = r0*64 + ((quad ^ (lx & 7)) << 3);
    // V B-fragment read base: row = nt*16+lx; g(row) == gv
    const int gv  = (lx & 3) ^ (((lx >> 3) & 1) << 2);
    const int va0 = lx*64 + ((quad ^ gv) << 3);

    f32x4 o[2][4];
#pragma unroll
    for (int qb = 0; qb < 2; ++qb)
#pragma unroll
        for (int nt = 0; nt < 4; ++nt) o[qb][nt] = (f32x4){0.f, 0.f, 0.f, 0.f};
    float mrun[2] = {-INFINITY, -INFINITY};
    float lrun[2] = {0.f, 0.f};        // per-lane PARTIAL sums (reduced at end)

    s16x8 rkh0, rkh1, rvh0, rvh1;
    rkh0 = *(const s16x8*)&Khf [kg0];
    rkh1 = *(const s16x8*)&Khf [kg0 + (size_t)8*HD];
    rvh0 = *(const s16x8*)&Vthf[vg0];
    rvh1 = *(const s16x8*)&Vthf[vg0 + (size_t)8*T_SEQ];
    *(s16x8*)&KH[lw0] = rkh0;  *(s16x8*)&KH[lw1] = rkh1;
    *(s16x8*)&VH[lw0] = rvh0;  *(s16x8*)&VH[lw1] = rvh1;
    __syncthreads();

    for (int kt = 0; kt < T_SEQ/64; ++kt) {
        const int ktn = (kt+1 < T_SEQ/64) ? kt+1 : kt;
        const size_t kgt = kg0 + (size_t)ktn*64*HD;
        const size_t vgt = vg0 + ktn*64;
        rkh0 = *(const s16x8*)&Khf [kgt];
        rkh1 = *(const s16x8*)&Khf [kgt + (size_t)8*HD];
        rvh0 = *(const s16x8*)&Vthf[vgt];
        rvh1 = *(const s16x8*)&Vthf[vgt + (size_t)8*T_SEQ];

        // mask C-in seeds from LDS (broadcast within each 16-lane quad group)
        f32x4 mb[4];
#pragma unroll
        for (int nt = 0; nt < 4; ++nt)
            mb[nt] = *(const f32x4*)&MB[kt*64 + (quad << 3) + ((nt >> 1) << 5) + ((nt & 1) << 2)];

        // ---- QK^T (single fp16 K as A operand; mask bias as C-in) ----
        f32x4 s[2][4];
        __builtin_amdgcn_s_setprio(1);
#pragma unroll
        for (int nt = 0; nt < 4; ++nt) {
            const int a0 = ka0 + ((nt & 1) << 8) + ((nt >> 1) << 11);
            const f16x8 kh0 = *(const f16x8*)&KH[a0];
            const f16x8 kh1 = *(const f16x8*)&KH[a0 ^ 32];
            s[0][nt] = mb[nt];
            s[1][nt] = mb[nt];
            s[0][nt] = __builtin_amdgcn_mfma_f32_16x16x32_f16(kh0, qf[0][0], s[0][nt], 0, 0, 0);
            s[0][nt] = __builtin_amdgcn_mfma_f32_16x16x32_f16(kh1, qf[0][1], s[0][nt], 0, 0, 0);
            s[1][nt] = __builtin_amdgcn_mfma_f32_16x16x32_f16(kh0, qf[1][0], s[1][nt], 0, 0, 0);
            s[1][nt] = __builtin_amdgcn_mfma_f32_16x16x32_f16(kh1, qf[1][1], s[1][nt], 0, 0, 0);
        }
        __builtin_amdgcn_s_setprio(0);

        // ---- online softmax per q-block: row t=lx lane-local across quads ----
        float mt[2];
#pragma unroll
        for (int qb = 0; qb < 2; ++qb) {
            const float m0q = fmaxf(fmaxf(s[qb][0][0], s[qb][0][1]), fmaxf(s[qb][0][2], s[qb][0][3]));
            const float m1q = fmaxf(fmaxf(s[qb][1][0], s[qb][1][1]), fmaxf(s[qb][1][2], s[qb][1][3]));
            const float m2q = fmaxf(fmaxf(s[qb][2][0], s[qb][2][1]), fmaxf(s[qb][2][2], s[qb][2][3]));
            const float m3q = fmaxf(fmaxf(s[qb][3][0], s[qb][3][1]), fmaxf(s[qb][3][2], s[qb][3][3]));
            float m = fmaxf(fmaxf(m0q, m1q), fmaxf(m2q, m3q));
            m = fmaxf(m, __shfl_xor(m, 16));
            m = fmaxf(m, __shfl_xor(m, 32));
            mt[qb] = m;
        }

        // defer-max (T13): skip rescale while max growth <= 8 for BOTH blocks
        const bool stable = (mt[0] - mrun[0] <= 8.0f) && (mt[1] - mrun[1] <= 8.0f);
        if (!__all(stable)) {
#pragma unroll
            for (int qb = 0; qb < 2; ++qb) {
                const float mnew  = fmaxf(mrun[qb], mt[qb]);
                const float alpha = exp2_raw(mrun[qb] - mnew);
                mrun[qb] = mnew;
                lrun[qb] *= alpha;      // partial sums scale by row-uniform alpha
                float ar[4];
#pragma unroll
                for (int r = 0; r < 4; ++r)
                    ar[r] = __shfl(alpha, (ln & 48) | ((quad << 2) + r));
#pragma unroll
                for (int nt = 0; nt < 4; ++nt)
#pragma unroll
                    for (int r = 0; r < 4; ++r) o[qb][nt][r] *= ar[r];
            }
        }

        union PU { unsigned u[4]; f16x8 v; };
        PU pf[2][2];
#pragma unroll
        for (int qb = 0; qb < 2; ++qb) {
            float lt = 0.f;
#pragma unroll
            for (int nt = 0; nt < 4; ++nt)
#pragma unroll
                for (int r = 0; r < 4; ++r) {
                    s[qb][nt][r] = exp2_raw(s[qb][nt][r] - mrun[qb]);
                    lt += s[qb][nt][r];
                }
            lrun[qb] += lt;             // per-lane partial; cross-quad at end

            // pack P -> fp16 A-fragments via v_cvt_pkrtz (1 op / 2 vals)
            pf[qb][0].u[0] = pkrtz(s[qb][0][0], s[qb][0][1]);
            pf[qb][0].u[1] = pkrtz(s[qb][0][2], s[qb][0][3]);
            pf[qb][0].u[2] = pkrtz(s[qb][1][0], s[qb][1][1]);
            pf[qb][0].u[3] = pkrtz(s[qb][1][2], s[qb][1][3]);   // k 0..31
            pf[qb][1].u[0] = pkrtz(s[qb][2][0], s[qb][2][1]);
            pf[qb][1].u[1] = pkrtz(s[qb][2][2], s[qb][2][3]);
            pf[qb][1].u[2] = pkrtz(s[qb][3][0], s[qb][3][1]);
            pf[qb][1].u[3] = pkrtz(s[qb][3][2], s[qb][3][3]);   // k 32..63
        }

        // ---- PV (single fp16 V; each V fragment feeds both q-blocks) ----
        __builtin_amdgcn_s_setprio(1);
#pragma unroll
        for (int nt = 0; nt < 4; ++nt) {
            const int v0 = va0 + (nt << 10);
            const f16x8 vh0 = *(const f16x8*)&VH[v0];
            const f16x8 vh1 = *(const f16x8*)&VH[v0 ^ 32];
            o[0][nt] = __builtin_amdgcn_mfma_f32_16x16x32_f16(pf[0][0].v, vh0, o[0][nt], 0, 0, 0);
            o[0][nt] = __builtin_amdgcn_mfma_f32_16x16x32_f16(pf[0][1].v, vh1, o[0][nt], 0, 0, 0);
            o[1][nt] = __builtin_amdgcn_mfma_f32_16x16x32_f16(pf[1][0].v, vh0, o[1][nt], 0, 0, 0);
            o[1][nt] = __builtin_amdgcn_mfma_f32_16x16x32_f16(pf[1][1].v, vh1, o[1][nt], 0, 0, 0);
        }
        __builtin_amdgcn_s_setprio(0);

        __syncthreads();
        *(s16x8*)&KH[lw0] = rkh0;  *(s16x8*)&KH[lw1] = rkh1;
        *(s16x8*)&VH[lw0] = rvh0;  *(s16x8*)&VH[lw1] = rvh1;
        __syncthreads();
    }

    // ---- final cross-quad l reduce + normalize + fp16 store ----
#pragma unroll
    for (int qb = 0; qb < 2; ++qb) {
        lrun[qb] += __shfl_xor(lrun[qb], 16);
        lrun[qb] += __shfl_xor(lrun[qb], 32);
        const float linv = 1.0f / lrun[qb];
        float ir[4];
#pragma unroll
        for (int r = 0; r < 4; ++r)
            ir[r] = __shfl(linv, (ln & 48) | ((quad << 2) + r));
#pragma unroll
        for (int nt = 0; nt < 4; ++nt)
#pragma unroll
            for (int r = 0; r < 4; ++r) {
                const int t = qrow0 + qb*16 + quad*4 + r;
                const float res = o[qb][nt][r] * ir[r];
                const size_t off = (((size_t)b)*T_SEQ + t)*DM + h*HD + nt*16 + lx;
                AOf[off] = f2h(res);
            }
    }
}

// -------------------------------------------------------------------------
// Memory plan: d_ws 128.03 MiB + d_out as scratch.
//   d_ws slots (16 MiB each): Qf | Khf | Vthf | (free x3) |
//         MSK 32 KiB | 32-MiB region R: WqkvTh (6 MiB, dead after
//         QKV GEMM) then AOf (16 MiB, attention output)
//   d_out: TokF (16 MiB) — dead after QKV GEMM
//   WoutTh <- Khf slot (dead after attention)
// -------------------------------------------------------------------------
extern "C" void kernel_launch(void* const* d_in, const int* in_sizes, int n_in,
                              void* d_out, int out_size, void* d_ws, size_t ws_size,
                              hipStream_t stream)
{
    const float* tokens = (const float*)d_in[0];
    const int*   pad    = (const int*)d_in[1];
    const float* Wqkv   = (const float*)d_in[2];
    const float* bqkv   = (const float*)d_in[3];
    const float* Wout   = (const float*)d_in[4];
    const float* bout   = (const float*)d_in[5];
    float* out = (float*)d_out;

    const size_t SZ = (size_t)8388608;
    ushort_t* U = (ushort_t*)d_ws;
    ushort_t* Qf   = U;
    ushort_t* Khf  = U + SZ;
    ushort_t* Vthf = U + 2*SZ;
    float* MSK = (float*)(U + 6*SZ);
    ushort_t* R   = (ushort_t*)(MSK + 8192);       // 32-MiB region
    ushort_t* WqkvTh = R;
    ushort_t* AOf = R;                             // overlays dead WqkvTh
    ushort_t* TokF = (ushort_t*)d_out;             // scratch in d_out
    ushort_t* WoutTh = Khf;                        // dead after attention

    maskprep_kernel<<<dim3(BATCH), dim3(256), 0, stream>>>(pad, MSK);
    split_kernel<<<dim3(8192), dim3(256), 0, stream>>>(tokens, TokF);
    transpose_h_kernel<<<dim3(48, 16), dim3(256), 0, stream>>>(
        Wqkv, WqkvTh, DM, 3*DM);
    mfma_gemm_kernel<1><<<dim3(24, 128), dim3(256), 0, stream>>>(
        TokF, WqkvTh, bqkv, nullptr,
        Qf, Khf, Vthf, BATCH*T_SEQ, 3*DM, DM);
    attn_mfma_kernel<<<dim3(1024), dim3(256), 0, stream>>>(
        Qf, Khf, Vthf, MSK, AOf);
    transpose_h_kernel<<<dim3(16, 16), dim3(256), 0, stream>>>(
        Wout, WoutTh, DM, DM);
    mfma_gemm_kernel<0><<<dim3(8, 128), dim3(256), 0, stream>>>(
        AOf, WoutTh, bout, out,
        nullptr, nullptr, nullptr, BATCH*T_SEQ, DM, DM);
}

// Round 10
// 327.032 us; speedup vs baseline: 1.5027x; 1.0133x over previous
//
#include <hip/hip_runtime.h>
#include <cmath>

#define T_SEQ 2048
#define NH    16
#define HD    64
#define DM    1024
#define BATCH 4

typedef __attribute__((ext_vector_type(8))) short s16x8;
typedef __attribute__((ext_vector_type(8))) _Float16 f16x8;
typedef __attribute__((ext_vector_type(2))) __fp16 fp16v2;
typedef __attribute__((ext_vector_type(4))) float f32x4;
typedef unsigned short ushort_t;

__device__ __forceinline__ ushort_t f2h(float x) {   // rne fp32->fp16
    union { _Float16 h; ushort_t u; } v; v.h = (_Float16)x; return v.u;
}
__device__ __forceinline__ float h2f(ushort_t u) {
    union { ushort_t u; _Float16 h; } v; v.u = u; return (float)v.h;
}
// raw v_exp_f32 (2^x)
__device__ __forceinline__ float exp2_raw(float x) {
    return __builtin_amdgcn_exp2f(x);
}
// packed fp32x2 -> fp16x2 (RTZ), one instruction (v_cvt_pkrtz_f16_f32).
// NOTE: builtin returns __fp16 ext_vector(2) — union must match (R6 fail).
__device__ __forceinline__ unsigned pkrtz(float a, float b) {
    union { fp16v2 h; unsigned u; } v;
    v.h = __builtin_amdgcn_cvt_pkrtz(a, b);
    return v.u;
}

// async global->LDS DMA, 16 B per lane (verified R7/R9).
__device__ __forceinline__ void dma16(const void* g, const void* l) {
    __builtin_amdgcn_global_load_lds(
        (const __attribute__((address_space(1))) unsigned int*)(unsigned long long)g,
        (__attribute__((address_space(3))) unsigned int*)(unsigned int)(unsigned long long)l,
        16, 0, 0);
}

// -------------------------------------------------------------------------
// Kernel 1: mask prep. Emits ADDITIVE bias: 0.0 (attend) / -1e30 (pad).
// -------------------------------------------------------------------------
__global__ void maskprep_kernel(const int* __restrict__ pad, float* __restrict__ valid)
{
    __shared__ int sall[256];
    const int b = blockIdx.x;
    const int t = threadIdx.x;
    int allp = 1;
    for (int i = t; i < T_SEQ; i += 256) allp &= (pad[b*T_SEQ + i] != 0) ? 1 : 0;
    sall[t] = allp;
    __syncthreads();
    for (int s = 128; s > 0; s >>= 1) {
        if (t < s) sall[t] &= sall[t + s];
        __syncthreads();
    }
    const int ap = sall[0];
    for (int i = t; i < T_SEQ; i += 256) {
        const int p = (pad[b*T_SEQ + i] != 0) ? 1 : 0;
        valid[b*T_SEQ + i] = (p && !ap) ? -1e30f : 0.0f;
    }
}

// -------------------------------------------------------------------------
// Kernel 2: weight transpose. W[K][N] -> Th[N][K] as SINGLE fp16 of (32*w).
// GEMM epilogue multiplies acc by 1/32.
// -------------------------------------------------------------------------
__global__ __launch_bounds__(256)
void transpose_h_kernel(const float* __restrict__ W,
                        ushort_t* __restrict__ Th, int K, int N)
{
    __shared__ float T[64][68];
    const int tid = threadIdx.x;
    const int n0 = blockIdx.x * 64;
    const int k0 = blockIdx.y * 64;
#pragma unroll
    for (int i = 0; i < 4; ++i) {
        const int kr = (tid >> 4) + i*16;
        const int nc = (tid & 15) * 4;
        const float4 v = *(const float4*)&W[(size_t)(k0 + kr)*N + n0 + nc];
        T[nc+0][kr] = v.x; T[nc+1][kr] = v.y; T[nc+2][kr] = v.z; T[nc+3][kr] = v.w;
    }
    __syncthreads();
#pragma unroll
    for (int i = 0; i < 4; ++i) {
        const int nr = (tid >> 4) + i*16;
        const int kc = (tid & 15) * 4;
        ushort_t h[4];
#pragma unroll
        for (int j = 0; j < 4; ++j) h[j] = f2h(T[nr][kc + j] * 32.0f);
        const size_t off = (size_t)(n0 + nr)*K + k0 + kc;
        *(short4*)&Th[off] = make_short4((short)h[0], (short)h[1], (short)h[2], (short)h[3]);
    }
}

// -------------------------------------------------------------------------
// Kernel 2b: row-major fp32 -> single fp16 (tokens).
// -------------------------------------------------------------------------
__global__ __launch_bounds__(256)
void split_kernel(const float* __restrict__ X, ushort_t* __restrict__ H)
{
    const int i = blockIdx.x * 256 + threadIdx.x;     // float4 index
    const float4 v = ((const float4*)X)[i];
    *(short4*)&H[(size_t)i*4] = make_short4(
        (short)f2h(v.x), (short)f2h(v.y), (short)f2h(v.z), (short)f2h(v.w));
}

// -------------------------------------------------------------------------
// Kernel 3/5: single-fp16 MFMA GEMM. R10: counted-vmcnt pipeline (T3/T4):
// 4 LDS buffers, prefetch depth 2, per step {ISSUE(k+2); s_waitcnt
// vmcnt(6); raw s_barrier; ds_read buf[k]; MFMA}. vmcnt(6) waits only for
// step k's DMAs (issued 2 iterations ago -> latency fully covered); the
// compiler's vmcnt(0) drain is gone from the loop.
// Hazards: RAW safe (vmcnt(6)+barrier before reads); WAR safe (buffer
// written at iter k was last read at iter k-2, complete before
// barrier(k-1) which the issuer passed). Tail: clamped issue into a
// never-read buffer keeps vmcnt count uniform; __syncthreads after loop
// drains before the epilogue overlays smem.
// -------------------------------------------------------------------------
template<int EPI>
__global__ __launch_bounds__(256)
void mfma_gemm_kernel(const ushort_t* __restrict__ Atf,
                      const ushort_t* __restrict__ BTh,
                      const float* __restrict__ bias,
                      float* __restrict__ O0,
                      ushort_t* __restrict__ Qf,
                      ushort_t* __restrict__ Khf,
                      ushort_t* __restrict__ Vthf,
                      int M, int N, int K)
{
    __shared__ __align__(16) char smem[49152];
    char* smA0 = smem;              // 4 x [64][32] fp16 = 4 KB each
    char* smA1 = smem + 4096;
    char* smA2 = smem + 8192;
    char* smA3 = smem + 12288;
    char* smB0 = smem + 16384;      // 4 x [128][32] fp16 = 8 KB each
    char* smB1 = smem + 24576;
    char* smB2 = smem + 32768;
    char* smB3 = smem + 40960;      // K-loop uses 48 KB; epilogue overlays

    const int tid  = threadIdx.x;
    const int w    = tid >> 6;
    const int ln   = tid & 63;
    const int lx   = ln & 15;
    const int quad = ln >> 4;
    const int mw   = (w >> 1) * 32;
    const int nw   = (w & 1) * 64;
    const int m0   = blockIdx.y * 64;
    const int n0   = blockIdx.x * 128;

    // staging: lane ln -> row base+(ln>>2), LDS chunk ln&3 [linear dest].
    // source chunk pre-swizzled: (ln&3) ^ ((ln>>3)&3)  [= (row>>1)&3]
    const int swc = ((ln & 3) ^ ((ln >> 3) & 3)) * 8;
    const size_t gaA = (size_t)(m0 + w*16 + (ln >> 2))*K + swc;
    const size_t gaB = (size_t)(n0 + w*32 + (ln >> 2))*K + swc;
    const int ldsA = (w*64 + ln)*16;
    const int ldsB = (w*128 + ln)*16;

#define ISSUE_DMA(kk, dA, dB) do {                                       \
        dma16(Atf + gaA + (kk),        (dA) + ldsA);                     \
        dma16(BTh + gaB + (kk),        (dB) + ldsB);                     \
        dma16(BTh + gaB + 16*K + (kk), (dB) + ldsB + 1024);              \
    } while (0)

    f32x4 acc[2][4];
#pragma unroll
    for (int mt = 0; mt < 2; ++mt)
#pragma unroll
        for (int nt = 0; nt < 4; ++nt) acc[mt][nt] = (f32x4){0.f,0.f,0.f,0.f};

    // read-side swizzled chunk: (row>>1)&3 == (lx>>1)&3 for all fragments
    const int cs = (quad ^ ((lx >> 1) & 3)) * 16;

#define GEMM_STEP(kk, cA, cB, nA, nB) do {                                \
        const int kkp = ((kk) + 64 < K) ? (kk) + 64 : K - 32;             \
        ISSUE_DMA(kkp, nA, nB);                                           \
        asm volatile("s_waitcnt vmcnt(6)" ::: "memory");                  \
        __builtin_amdgcn_s_barrier();                                     \
        f16x8 bfh[4];                                                     \
        _Pragma("unroll")                                                 \
        for (int nt = 0; nt < 4; ++nt)                                    \
            bfh[nt] = *(const f16x8*)((cB) + (nw + nt*16 + lx)*64 + cs);  \
        const f16x8 af0 = *(const f16x8*)((cA) + (mw + lx)*64 + cs);      \
        const f16x8 af1 = *(const f16x8*)((cA) + (mw + 16 + lx)*64 + cs); \
        __builtin_amdgcn_s_setprio(1);                                    \
        _Pragma("unroll")                                                 \
        for (int nt = 0; nt < 4; ++nt) {                                  \
            acc[0][nt] = __builtin_amdgcn_mfma_f32_16x16x32_f16(af0, bfh[nt], acc[0][nt], 0, 0, 0); \
            acc[1][nt] = __builtin_amdgcn_mfma_f32_16x16x32_f16(af1, bfh[nt], acc[1][nt], 0, 0, 0); \
        }                                                                 \
        __builtin_amdgcn_s_setprio(0);                                    \
    } while (0)

    ISSUE_DMA(0,  smA0, smB0);
    ISSUE_DMA(32, smA1, smB1);
    for (int kk = 0; kk < K; kk += 128) {
        GEMM_STEP(kk,      smA0, smB0, smA2, smB2);
        GEMM_STEP(kk+32,   smA1, smB1, smA3, smB3);
        GEMM_STEP(kk+64,   smA2, smB2, smA0, smB0);
        GEMM_STEP(kk+96,   smA3, smB3, smA1, smB1);
    }
#undef GEMM_STEP
#undef ISSUE_DMA
    __syncthreads();   // drain in-flight clamped DMAs before smem reuse

    const float INV32 = 0.03125f;
    // ---------------- epilogue ----------------
    if (EPI == 0) {
#pragma unroll
        for (int nt = 0; nt < 4; ++nt) {
            const int n = n0 + nw + nt*16 + lx;
#pragma unroll
            for (int mt = 0; mt < 2; ++mt)
#pragma unroll
                for (int r = 0; r < 4; ++r) {
                    const int m = m0 + mw + mt*16 + quad*4 + r;
                    O0[(size_t)m*N + n] = acc[mt][nt][r]*INV32 + bias[n];
                }
        }
    } else {
        const int which = n0 >> 10;           // block-uniform: 0=q 1=k 2=v
        const int hbase = (n0 & 1023) >> 6;
        const int b     = m0 >> 11;
        const int t0    = m0 & 2047;
        float* Ct = (float*)smem;             // Q/K: [64][132]; V: [128][68]
        const float ssign = (lx & 1) ? 1.0f : -1.0f;

        if (which < 2) {
#pragma unroll
            for (int nt = 0; nt < 4; ++nt) {
                const int nl = nw + nt*16 + lx;
                const int d  = nl & 63;
                const float bn = bias[n0 + nl];
                const float freq = expf(-(float)(d >> 1) * 0.28782313662425575f);
#pragma unroll
                for (int mt = 0; mt < 2; ++mt)
#pragma unroll
                    for (int r = 0; r < 4; ++r) {
                        const int ml = mw + mt*16 + quad*4 + r;
                        const int t  = t0 + ml;
                        float res = acc[mt][nt][r]*INV32 + bn;
                        const float ang = (float)t * freq;
                        const float sn = sinf(ang), cs2 = cosf(ang);
                        const float prt = __shfl_xor(res, 1);
                        res = res*cs2 + ssign*prt*sn;
                        // Q scale folds 1/sqrt(hd) AND log2(e): softmax in exp2 domain
                        if (which == 0) res *= 0.18033688011112042f;
                        Ct[ml*132 + nl] = res;
                    }
            }
        } else {
#pragma unroll
            for (int nt = 0; nt < 4; ++nt) {
                const int nl = nw + nt*16 + lx;
                const float bn = bias[n0 + nl];
#pragma unroll
                for (int mt = 0; mt < 2; ++mt)
#pragma unroll
                    for (int r = 0; r < 4; ++r) {
                        const int ml = mw + mt*16 + quad*4 + r;
                        Ct[nl*68 + ml] = acc[mt][nt][r]*INV32 + bn;
                    }
            }
        }
        __syncthreads();

        if (which < 2) {
#pragma unroll
            for (int u = 0; u < 4; ++u) {
                const int L  = u*32 + (tid >> 3);
                const int t  = L & 63;
                const int hl = L >> 6;
                const int dg = (tid & 7) * 8;
                const float* src = &Ct[t*132 + hl*64 + dg];
                float v[8];
                *(f32x4*)&v[0] = *(const f32x4*)src;
                *(f32x4*)&v[4] = *(const f32x4*)(src + 4);
                s16x8 h8;
#pragma unroll
                for (int j = 0; j < 8; ++j) h8[j] = (short)f2h(v[j]);
                const int bh = b*NH + hbase + hl;
                const size_t off = (((size_t)bh)*T_SEQ + t0 + t)*64 + dg;
                if (which == 0) *(s16x8*)&Qf [off] = h8;
                else            *(s16x8*)&Khf[off] = h8;
            }
        } else {
#pragma unroll
            for (int u = 0; u < 4; ++u) {
                const int row = u*32 + (tid >> 3);
                const int d   = row & 63;
                const int hl  = row >> 6;
                const int tg  = (tid & 7) * 8;
                const float* src = &Ct[row*68 + tg];
                float v[8];
                *(f32x4*)&v[0] = *(const f32x4*)src;
                *(f32x4*)&v[4] = *(const f32x4*)(src + 4);
                s16x8 h8;
#pragma unroll
                for (int j = 0; j < 8; ++j) h8[j] = (short)f2h(v[j]);
                const int bh = b*NH + hbase + hl;
                const size_t off = (((size_t)bh)*HD + d)*T_SEQ + t0 + tg;
                *(s16x8*)&Vthf[off] = h8;
            }
        }
    }
}

// -------------------------------------------------------------------------
// Kernel 4: flash attention (R7 structure, unchanged). Pure fp16 K/V,
// 32 MFMA/wave-tile, LDS 24 KB, mask row in LDS, deferred l-reduce,
// pkrtz P pack, defer-max, setprio.
// -------------------------------------------------------------------------
__global__ __launch_bounds__(256, 3)
void attn_mfma_kernel(const ushort_t* __restrict__ Qf,
                      const ushort_t* __restrict__ Khf,
                      const ushort_t* __restrict__ Vthf,
                      const float* __restrict__ mbias,
                      ushort_t* __restrict__ AOf)
{
    __shared__ ushort_t KH[64*64];    // 8 KB
    __shared__ ushort_t VH[64*64];    // 8 KB
    __shared__ float    MB[T_SEQ];    // 8 KB mask row for this batch

    const int tid  = threadIdx.x;
    const int w    = tid >> 6;          // 0..3
    const int ln   = tid & 63;
    const int lx   = ln & 15;
    const int quad = ln >> 4;

    // 1024 blocks: id&7 = bh low bits (XCD), (id>>3)&15 = qt, id>>7 = bh hi
    const int id = blockIdx.x;
    const int qt = (id >> 3) & 15;
    const int bh = ((id >> 7) << 3) | (id & 7);
    const int b  = bh >> 4;
    const int h  = bh & 15;
    const int qrow0 = qt*128 + w*32;

    // Q fragments (B operand, single fp16), 2 q-blocks of 16 rows
    f16x8 qf[2][2];
#pragma unroll
    for (int qb = 0; qb < 2; ++qb) {
        const size_t qo = (((size_t)bh)*T_SEQ + qrow0 + qb*16 + lx)*HD + quad*8;
        qf[qb][0] = *(const f16x8*)&Qf[qo];
        qf[qb][1] = *(const f16x8*)&Qf[qo + 32];
    }

    // mask row -> LDS (coalesced, once per block)
    {
        const f32x4* msrc = (const f32x4*)(mbias + (size_t)b*T_SEQ);
        f32x4* mdst = (f32x4*)MB;
#pragma unroll
        for (int i = 0; i < 2; ++i) mdst[tid + i*256] = msrc[tid + i*256];
    }

    // staging: wave w stages rows [w*16, w*16+16) in two 8-row groups.
    // g(row) = (row&3) ^ (((row>>3)&1)<<2)
    const int sj   = ln >> 3;           // 0..7
    const int sch  = ln & 7;
    const int srow = w*16 + sj;
    const size_t kg0 = ((size_t)bh*T_SEQ + srow)*HD + sch*8;
    const size_t vg0 = ((size_t)bh*HD + srow)*T_SEQ + sch*8;
    const int lw0 = srow*64 + ((sch ^ (sj & 3)) << 3);
    const int lw1 = (srow + 8)*64 + ((sch ^ (sj & 3) ^ 4) << 3);

    // K A-fragment read base: row(nt=0) = 8*(lx>>2)+(lx&3); g(row) == lx&7
    const int r0  = ((lx >> 2) << 3) + (lx & 3);
    const int ka0 = r0*64 + ((quad ^ (lx & 7)) << 3);
    // V B-fragment read base: row = nt*16+lx; g(row) == gv
    const int gv  = (lx & 3) ^ (((lx >> 3) & 1) << 2);
    const int va0 = lx*64 + ((quad ^ gv) << 3);

    f32x4 o[2][4];
#pragma unroll
    for (int qb = 0; qb < 2; ++qb)
#pragma unroll
        for (int nt = 0; nt < 4; ++nt) o[qb][nt] = (f32x4){0.f, 0.f, 0.f, 0.f};
    float mrun[2] = {-INFINITY, -INFINITY};
    float lrun[2] = {0.f, 0.f};        // per-lane PARTIAL sums (reduced at end)

    s16x8 rkh0, rkh1, rvh0, rvh1;
    rkh0 = *(const s16x8*)&Khf [kg0];
    rkh1 = *(const s16x8*)&Khf [kg0 + (size_t)8*HD];
    rvh0 = *(const s16x8*)&Vthf[vg0];
    rvh1 = *(const s16x8*)&Vthf[vg0 + (size_t)8*T_SEQ];
    *(s16x8*)&KH[lw0] = rkh0;  *(s16x8*)&KH[lw1] = rkh1;
    *(s16x8*)&VH[lw0] = rvh0;  *(s16x8*)&VH[lw1] = rvh1;
    __syncthreads();

    for (int kt = 0; kt < T_SEQ/64; ++kt) {
        const int ktn = (kt+1 < T_SEQ/64) ? kt+1 : kt;
        const size_t kgt = kg0 + (size_t)ktn*64*HD;
        const size_t vgt = vg0 + ktn*64;
        rkh0 = *(const s16x8*)&Khf [kgt];
        rkh1 = *(const s16x8*)&Khf [kgt + (size_t)8*HD];
        rvh0 = *(const s16x8*)&Vthf[vgt];
        rvh1 = *(const s16x8*)&Vthf[vgt + (size_t)8*T_SEQ];

        // mask C-in seeds from LDS (broadcast within each 16-lane quad group)
        f32x4 mb[4];
#pragma unroll
        for (int nt = 0; nt < 4; ++nt)
            mb[nt] = *(const f32x4*)&MB[kt*64 + (quad << 3) + ((nt >> 1) << 5) + ((nt & 1) << 2)];

        // ---- QK^T (single fp16 K as A operand; mask bias as C-in) ----
        f32x4 s[2][4];
        __builtin_amdgcn_s_setprio(1);
#pragma unroll
        for (int nt = 0; nt < 4; ++nt) {
            const int a0 = ka0 + ((nt & 1) << 8) + ((nt >> 1) << 11);
            const f16x8 kh0 = *(const f16x8*)&KH[a0];
            const f16x8 kh1 = *(const f16x8*)&KH[a0 ^ 32];
            s[0][nt] = mb[nt];
            s[1][nt] = mb[nt];
            s[0][nt] = __builtin_amdgcn_mfma_f32_16x16x32_f16(kh0, qf[0][0], s[0][nt], 0, 0, 0);
            s[0][nt] = __builtin_amdgcn_mfma_f32_16x16x32_f16(kh1, qf[0][1], s[0][nt], 0, 0, 0);
            s[1][nt] = __builtin_amdgcn_mfma_f32_16x16x32_f16(kh0, qf[1][0], s[1][nt], 0, 0, 0);
            s[1][nt] = __builtin_amdgcn_mfma_f32_16x16x32_f16(kh1, qf[1][1], s[1][nt], 0, 0, 0);
        }
        __builtin_amdgcn_s_setprio(0);

        // ---- online softmax per q-block: row t=lx lane-local across quads ----
        float mt[2];
#pragma unroll
        for (int qb = 0; qb < 2; ++qb) {
            const float m0q = fmaxf(fmaxf(s[qb][0][0], s[qb][0][1]), fmaxf(s[qb][0][2], s[qb][0][3]));
            const float m1q = fmaxf(fmaxf(s[qb][1][0], s[qb][1][1]), fmaxf(s[qb][1][2], s[qb][1][3]));
            const float m2q = fmaxf(fmaxf(s[qb][2][0], s[qb][2][1]), fmaxf(s[qb][2][2], s[qb][2][3]));
            const float m3q = fmaxf(fmaxf(s[qb][3][0], s[qb][3][1]), fmaxf(s[qb][3][2], s[qb][3][3]));
            float m = fmaxf(fmaxf(m0q, m1q), fmaxf(m2q, m3q));
            m = fmaxf(m, __shfl_xor(m, 16));
            m = fmaxf(m, __shfl_xor(m, 32));
            mt[qb] = m;
        }

        // defer-max (T13): skip rescale while max growth <= 8 for BOTH blocks
        const bool stable = (mt[0] - mrun[0] <= 8.0f) && (mt[1] - mrun[1] <= 8.0f);
        if (!__all(stable)) {
#pragma unroll
            for (int qb = 0; qb < 2; ++qb) {
                const float mnew  = fmaxf(mrun[qb], mt[qb]);
                const float alpha = exp2_raw(mrun[qb] - mnew);
                mrun[qb] = mnew;
                lrun[qb] *= alpha;      // partial sums scale by row-uniform alpha
                float ar[4];
#pragma unroll
                for (int r = 0; r < 4; ++r)
                    ar[r] = __shfl(alpha, (ln & 48) | ((quad << 2) + r));
#pragma unroll
                for (int nt = 0; nt < 4; ++nt)
#pragma unroll
                    for (int r = 0; r < 4; ++r) o[qb][nt][r] *= ar[r];
            }
        }

        union PU { unsigned u[4]; f16x8 v; };
        PU pf[2][2];
#pragma unroll
        for (int qb = 0; qb < 2; ++qb) {
            float lt = 0.f;
#pragma unroll
            for (int nt = 0; nt < 4; ++nt)
#pragma unroll
                for (int r = 0; r < 4; ++r) {
                    s[qb][nt][r] = exp2_raw(s[qb][nt][r] - mrun[qb]);
                    lt += s[qb][nt][r];
                }
            lrun[qb] += lt;             // per-lane partial; cross-quad at end

            // pack P -> fp16 A-fragments via v_cvt_pkrtz (1 op / 2 vals)
            pf[qb][0].u[0] = pkrtz(s[qb][0][0], s[qb][0][1]);
            pf[qb][0].u[1] = pkrtz(s[qb][0][2], s[qb][0][3]);
            pf[qb][0].u[2] = pkrtz(s[qb][1][0], s[qb][1][1]);
            pf[qb][0].u[3] = pkrtz(s[qb][1][2], s[qb][1][3]);   // k 0..31
            pf[qb][1].u[0] = pkrtz(s[qb][2][0], s[qb][2][1]);
            pf[qb][1].u[1] = pkrtz(s[qb][2][2], s[qb][2][3]);
            pf[qb][1].u[2] = pkrtz(s[qb][3][0], s[qb][3][1]);
            pf[qb][1].u[3] = pkrtz(s[qb][3][2], s[qb][3][3]);   // k 32..63
        }

        // ---- PV (single fp16 V; each V fragment feeds both q-blocks) ----
        __builtin_amdgcn_s_setprio(1);
#pragma unroll
        for (int nt = 0; nt < 4; ++nt) {
            const int v0 = va0 + (nt << 10);
            const f16x8 vh0 = *(const f16x8*)&VH[v0];
            const f16x8 vh1 = *(const f16x8*)&VH[v0 ^ 32];
            o[0][nt] = __builtin_amdgcn_mfma_f32_16x16x32_f16(pf[0][0].v, vh0, o[0][nt], 0, 0, 0);
            o[0][nt] = __builtin_amdgcn_mfma_f32_16x16x32_f16(pf[0][1].v, vh1, o[0][nt], 0, 0, 0);
            o[1][nt] = __builtin_amdgcn_mfma_f32_16x16x32_f16(pf[1][0].v, vh0, o[1][nt], 0, 0, 0);
            o[1][nt] = __builtin_amdgcn_mfma_f32_16x16x32_f16(pf[1][1].v, vh1, o[1][nt], 0, 0, 0);
        }
        __builtin_amdgcn_s_setprio(0);

        __syncthreads();
        *(s16x8*)&KH[lw0] = rkh0;  *(s16x8*)&KH[lw1] = rkh1;
        *(s16x8*)&VH[lw0] = rvh0;  *(s16x8*)&VH[lw1] = rvh1;
        __syncthreads();
    }

    // ---- final cross-quad l reduce + normalize + fp16 store ----
#pragma unroll
    for (int qb = 0; qb < 2; ++qb) {
        lrun[qb] += __shfl_xor(lrun[qb], 16);
        lrun[qb] += __shfl_xor(lrun[qb], 32);
        const float linv = 1.0f / lrun[qb];
        float ir[4];
#pragma unroll
        for (int r = 0; r < 4; ++r)
            ir[r] = __shfl(linv, (ln & 48) | ((quad << 2) + r));
#pragma unroll
        for (int nt = 0; nt < 4; ++nt)
#pragma unroll
            for (int r = 0; r < 4; ++r) {
                const int t = qrow0 + qb*16 + quad*4 + r;
                const float res = o[qb][nt][r] * ir[r];
                const size_t off = (((size_t)b)*T_SEQ + t)*DM + h*HD + nt*16 + lx;
                AOf[off] = f2h(res);
            }
    }
}

// -------------------------------------------------------------------------
// Memory plan: d_ws 128.03 MiB + d_out as scratch.
//   d_ws slots (16 MiB each): Qf | Khf | Vthf | (free x3) |
//         MSK 32 KiB | 32-MiB region R: WqkvTh (6 MiB, dead after
//         QKV GEMM) then AOf (16 MiB, attention output)
//   d_out: TokF (16 MiB) — dead after QKV GEMM
//   WoutTh <- Khf slot (dead after attention)
// -------------------------------------------------------------------------
extern "C" void kernel_launch(void* const* d_in, const int* in_sizes, int n_in,
                              void* d_out, int out_size, void* d_ws, size_t ws_size,
                              hipStream_t stream)
{
    const float* tokens = (const float*)d_in[0];
    const int*   pad    = (const int*)d_in[1];
    const float* Wqkv   = (const float*)d_in[2];
    const float* bqkv   = (const float*)d_in[3];
    const float* Wout   = (const float*)d_in[4];
    const float* bout   = (const float*)d_in[5];
    float* out = (float*)d_out;

    const size_t SZ = (size_t)8388608;
    ushort_t* U = (ushort_t*)d_ws;
    ushort_t* Qf   = U;
    ushort_t* Khf  = U + SZ;
    ushort_t* Vthf = U + 2*SZ;
    float* MSK = (float*)(U + 6*SZ);
    ushort_t* R   = (ushort_t*)(MSK + 8192);       // 32-MiB region
    ushort_t* WqkvTh = R;
    ushort_t* AOf = R;                             // overlays dead WqkvTh
    ushort_t* TokF = (ushort_t*)d_out;             // scratch in d_out
    ushort_t* WoutTh = Khf;                        // dead after attention

    maskprep_kernel<<<dim3(BATCH), dim3(256), 0, stream>>>(pad, MSK);
    split_kernel<<<dim3(8192), dim3(256), 0, stream>>>(tokens, TokF);
    transpose_h_kernel<<<dim3(48, 16), dim3(256), 0, stream>>>(
        Wqkv, WqkvTh, DM, 3*DM);
    mfma_gemm_kernel<1><<<dim3(24, 128), dim3(256), 0, stream>>>(
        TokF, WqkvTh, bqkv, nullptr,
        Qf, Khf, Vthf, BATCH*T_SEQ, 3*DM, DM);
    attn_mfma_kernel<<<dim3(1024), dim3(256), 0, stream>>>(
        Qf, Khf, Vthf, MSK, AOf);
    transpose_h_kernel<<<dim3(16, 16), dim3(256), 0, stream>>>(
        Wout, WoutTh, DM, DM);
    mfma_gemm_kernel<0><<<dim3(8, 128), dim3(256), 0, stream>>>(
        AOf, WoutTh, bout, out,
        nullptr, nullptr, nullptr, BATCH*T_SEQ, DM, DM);
}